// Round 12
// baseline (253.480 us; speedup 1.0000x reference)
//
#include <hip/hip_runtime.h>
#include <hip/hip_bf16.h>

typedef __hip_bfloat16 bf16;
typedef unsigned short ushort_t;
typedef unsigned char uchar_t;
typedef unsigned int uint_t;
typedef __attribute__((ext_vector_type(8))) short short8;
typedef __attribute__((ext_vector_type(4))) float fx4;
typedef __attribute__((ext_vector_type(4))) unsigned int uintx4;

#define BB 32
#define NN 128
#define FF 9
#define EE 8
#define HH 128
#define HD 256
#define NHEAD 4
#define DHEAD 64

__device__ __forceinline__ float us2f(ushort_t u) {
    return __uint_as_float(((unsigned int)u) << 16);
}
// truncation split: hi = trunc16(v), lo = v - hi (lo exact in f32)
__device__ __forceinline__ ushort_t f2us_tr(float f) {
    return (ushort_t)(__float_as_uint(f) >> 16);
}
__device__ __forceinline__ short8 pack4(uint_t w0, uint_t w1, uint_t w2, uint_t w3) {
    uintx4 u = (uintx4){w0, w1, w2, w3};
    return __builtin_bit_cast(short8, u);
}
// pair split: a -> low short of word, c -> high short (bit-identical to
// per-element f2us_tr path: keep = bits & 0xffff0000 == us2f(f2us_tr(x)))
__device__ __forceinline__ void pair_split(float a, float c, uint_t& hw, uint_t& lw) {
    uint_t ua = __float_as_uint(a), uc = __float_as_uint(c);
    uint_t ka = ua & 0xffff0000u, kc = uc & 0xffff0000u;
    float la = a - __uint_as_float(ka);
    float lc = c - __uint_as_float(kc);
    hw = (ua >> 16) | kc;
    lw = (__float_as_uint(la) >> 16) | (__float_as_uint(lc) & 0xffff0000u);
}
__device__ __forceinline__ uint_t pair_hi(float a, float c) {
    return (__float_as_uint(a) >> 16) | (__float_as_uint(c) & 0xffff0000u);
}

__global__ void TransformerConvNet_85315230367963_kernel() {}

__global__ void k_sent(float* out, float val) {
    out[blockIdx.x * 256 + threadIdx.x] = val;
}

// ---------------- K_prep_all: all independent prep work, ONE launch -------
// blocks [0,32):       per-b adjvT + slists + cnts + RANK -> tmapG
//                      (coalesced row reads + LDS transpose; the old
//                      column-gather was a 64-lane 512B-stride scatter)
// blocks [32,1056):    base = src @ W1[:17] + b1          (1024 blocks)
// blocks [1056,1312):  zero x0                            (256 blocks)
// blocks [1312,1344):  Wh' split hi/lo + W1s/cb           (32 blocks, 4 n/blk)
// blocks [1344,1600):  prepw layer1 (IN=128)              (256 blocks)
// blocks [1600,1856):  prepw layer2 (IN=256)              (256 blocks)
__global__ void __launch_bounds__(256) k_prep_all(
    const float* adj, float* adjvT, uchar_t* sl_s, float* sl_av, int* cnts,
    int* tmapG,
    const float* nf, const int* et, const float* emb, const float* W1,
    const float* b1, float* base, float* x0,
    const float* Wh, const float* g1, const float* be1, const float* bh,
    ushort_t* BhiG, ushort_t* BloG, float* W1s, float* cbv,
    const float* Wq1, const float* Wk1, const float* Wv1, const float* Ws1,
    ushort_t* WhA, ushort_t* WlA,
    const float* Wq2, const float* Wk2, const float* Wv2, const float* Ws2,
    ushort_t* WhB, ushort_t* WlB)
{
    __shared__ float tileF[128 * 33];     // 16.9 KB (section 1 only)
    __shared__ int   cntL[256];           // [t][sh]

    int blk = blockIdx.x;
    int tid = threadIdx.x;

    if (blk < 32) {
        // ---- per-b: adjvT + ballot-compacted lists + cnts + rank ----
        int b = blk;
        int wv = tid >> 6, lane = tid & 63;
        for (int c = 0; c < 4; c++) {          // 4 chunks of 32 t
            int t0c = c * 32;
            // coalesced read of 128 s x 32 t sub-block, masked, into LDS
#pragma unroll
            for (int pass = 0; pass < 16; pass++) {
                int s = pass * 8 + (tid >> 5);
                int tq = tid & 31;
                float a = adj[(b * NN + s) * NN + t0c + tq];
                float av = (a > 0.f && a < 1.0f) ? a : 0.f;
                tileF[s * 33 + tq] = av;
            }
            __syncthreads();
            // ballot per (t,sh) unit from conflict-free LDS columns
#pragma unroll
            for (int j = 0; j < 16; j++) {
                int u = wv * 16 + j;           // 64 units per chunk
                int tq = u >> 1, sh = u & 1;
                int t = t0c + tq;
                int s = sh * 64 + lane;
                float av = tileF[s * 33 + tq];
                adjvT[(b * NN + t) * NN + s] = av;
                unsigned long long mask = __ballot(av != 0.f);
                int key = (b * NN + t) * 2 + sh;
                if (av != 0.f) {
                    int pos = __popcll(mask & ((1ull << lane) - 1ull));
                    sl_s[key * 64 + pos] = (uchar_t)s;
                    sl_av[key * 64 + pos] = av;
                }
                if (lane == 0) {
                    int cv = (int)__popcll(mask);
                    cnts[key] = cv;
                    cntL[t * 2 + sh] = cv;
                    if (mask == 0ull) { sl_s[key * 64] = 0; sl_av[key * 64] = 0.f; }
                }
            }
            __syncthreads();
        }
        // rank (once per (b,sh); comparator identical to old in-econv rank)
        {
            int sh = tid >> 7, i = tid & 127;
            int ci = cntL[i * 2 + sh];
            int rank = 0;
            for (int j = 0; j < 128; j++) {
                int cj = cntL[j * 2 + sh];
                rank += (cj > ci) || (cj == ci && j < i);
            }
            tmapG[b * 256 + sh * 128 + rank] = i;
        }
    } else if (blk < 1056) {
        // ---- base rows (4 per block)
        int bblk = blk - 32;
        int c = tid & 127;
#pragma unroll
        for (int rr = 0; rr < 2; rr++) {
            int bs = bblk * 4 + rr * 2 + (tid >> 7);
            int ty = et[bs];
            float acc = b1[c];
            for (int f = 0; f < FF; f++)
                acc += nf[bs * FF + f] * W1[f * HH + c];
            for (int e2 = 0; e2 < EE; e2++)
                acc += emb[ty * EE + e2] * W1[(FF + e2) * HH + c];
            base[bs * HH + c] = acc;
        }
    } else if (blk < 1312) {
        // ---- zero x0 (524288 floats = 131072 float4)
        int zblk = blk - 1056;
        float4* p = (float4*)x0 + zblk * 512 + tid * 2;
        p[0] = (float4){0.f, 0.f, 0.f, 0.f};
        p[1] = (float4){0.f, 0.f, 0.f, 0.f};
    } else if (blk < 1344) {
        // ---- Wh' = g1*Wh split bf16 hi/lo, swizzled; W1s/cb (wave per n)
        int n = (blk - 1312) * 4 + (tid >> 6);
        int t = tid & 63;
        int sw = 8 * (n & 15);
        float s1 = 0.f, s2 = 0.f;
#pragma unroll
        for (int kk = 0; kk < 2; kk++) {
            int k = t + kk * 64;
            float w = Wh[k * HH + n];
            float wp = g1[k] * w;
            ushort_t hb = f2us_tr(wp);
            float lo = wp - us2f(hb);
            BhiG[n * HH + (k ^ sw)] = hb;
            BloG[n * HH + (k ^ sw)] = f2us_tr(lo);
            s1 += wp;
            s2 += be1[k] * w;
        }
        for (int m = 1; m < 64; m <<= 1) {
            s1 += __shfl_xor(s1, m);
            s2 += __shfl_xor(s2, m);
        }
        if (t == 0) { W1s[n] = s1; cbv[n] = s2 + bh[n]; }
    } else if (blk < 1600) {
        // ---- prepw layer 1 (IN = HH), key = (mat,n), wave per key
        int key = (blk - 1344) * 4 + (tid >> 6);
        int lane = tid & 63;
        int mat = key >> 8, n = key & 255;
        const float* W = (mat == 0) ? Wq1 : (mat == 1) ? Wk1 : (mat == 2) ? Wv1 : Ws1;
        ushort_t* hi = WhA + mat * 256 * HH;
        ushort_t* lo = WlA + mat * 256 * HH;
        int sw = 8 * (n & 15);
        for (int k = lane; k < HH; k += 64) {
            float w = W[k * HD + n];
            ushort_t hb = f2us_tr(w);
            float l = w - us2f(hb);
            hi[n * HH + (k ^ sw)] = hb;
            lo[n * HH + (k ^ sw)] = f2us_tr(l);
        }
    } else {
        // ---- prepw layer 2 (IN = HD)
        int key = (blk - 1600) * 4 + (tid >> 6);
        int lane = tid & 63;
        int mat = key >> 8, n = key & 255;
        const float* W = (mat == 0) ? Wq2 : (mat == 1) ? Wk2 : (mat == 2) ? Wv2 : Ws2;
        ushort_t* hi = WhB + mat * 256 * HD;
        ushort_t* lo = WlB + mat * 256 * HD;
        int sw = 8 * (n & 15);
        for (int k = lane; k < HD; k += 64) {
            float w = W[k * HD + n];
            ushort_t hb = f2us_tr(w);
            float l = w - us2f(hb);
            hi[n * HD + (k ^ sw)] = hb;
            lo[n * HD + (k ^ sw)] = f2us_tr(l);
        }
    }
}

// ---------------- K3: embed conv, MFMA, compacted + LENGTH-SORTED lists ----
// D[n][t] = Wh'^T (LDS, A-op) x raw relu(h1)^T (regs, B-op).  B col = lane nl.
// Columns grouped by DESCENDING list length via PRECOMPUTED tmapG (round-12:
// the in-block 128-iter serial rank ran redundantly in all 512 blocks and
// cost ~8 us; now a 16-entry load).  Complementary tier pairing: blocks i
// and i+256 co-reside per CU; for b >= 16 remap tt -> 7-tt so each CU runs
// (tier k, tier 7-k).  Bijective -> bit-identical.
// NO setprio (round-9 lesson).  LN1 POST-mfma via W1s correction.
__global__ void __launch_bounds__(256) k_econv_mfma(
    const uchar_t* sl_s, const float* sl_av, const int* cnts, const int* tmapG,
    const float* base, const float* W1,
    const ushort_t* BhiG, const ushort_t* BloG,
    const float* W1sg, const float* cbv,
    const float* ghp, const float* behp, float* x0)
{
    __shared__ __align__(16) ushort_t PhiPlo[2 * HH * HH];   // 64 KB
    __shared__ int tmap16[16];                               // rank -> t (tile)
    ushort_t* Phi = PhiPlo;
    ushort_t* Plo = PhiPlo + HH * HH;

    int blk = blockIdx.x;
    int b  = blk >> 4;
    int tt = (blk >> 1) & 7;
    int sh = blk & 1;
    if (b >= BB / 2) tt = 7 - tt;      // complementary tier pairing
    int t0 = tt * 16;
    int tid = threadIdx.x;
    int wv  = tid >> 6;
    int lane = tid & 63;
    int nl = lane & 15;
    int quad = lane >> 4;

    if (tid < 16) tmap16[tid] = tmapG[b * 256 + sh * 128 + t0 + tid];

    {
        const uint4* srcH = (const uint4*)BhiG;
        const uint4* srcL = (const uint4*)BloG;
        uint4* dstH = (uint4*)Phi;
        uint4* dstL = (uint4*)Plo;
        for (int i = tid; i < HH * HH / 8; i += 256) {
            dstH[i] = srcH[i];
            dstL[i] = srcL[i];
        }
    }

    float w17v[4][8];
#pragma unroll
    for (int st = 0; st < 4; st++) {
        const float* p = W1 + 17 * HH + quad * 8 + 32 * st;
        float4 a = *(const float4*)p;
        float4 bq = *(const float4*)(p + 4);
        w17v[st][0] = a.x;  w17v[st][1] = a.y;  w17v[st][2] = a.z;  w17v[st][3] = a.w;
        w17v[st][4] = bq.x; w17v[st][5] = bq.y; w17v[st][6] = bq.z; w17v[st][7] = bq.w;
    }

    __syncthreads();

    int myt = tmap16[nl];               // this lane's column t
    int key = ((b << 7) + myt) * 2 + sh;
    int cnt = cnts[key];
    int q = (cnt + 3) >> 2;              // per-wave chunk
    int mq = q;
#pragma unroll
    for (int m = 1; m < 16; m <<= 1) mq = max(mq, __shfl_xor(mq, m));
    const uchar_t* lst_s = sl_s + key * 64;
    const float*   lst_a = sl_av + key * 64;
    int i0 = wv * q;

    fx4 acc1[8];                 // sum_s mask*r2*h2   (per n, per col)
#pragma unroll
    for (int tile = 0; tile < 8; tile++) acc1[tile] = (fx4){0.f, 0.f, 0.f, 0.f};
    float c0 = 0.f;              // sum_s mask
    float c1 = 0.f;              // sum_s mask*r2*mean2

    for (int i = 0; i < mq; i++) {
        int idx = i0 + i;
        bool val = (i < q) && (idx < cnt);
        int ridx = (idx < cnt) ? idx : (cnt > 0 ? cnt - 1 : 0);
        int s = lst_s[ridx];
        float avv = val ? lst_a[ridx] : 0.f;
        const float* brow = base + (b * NN + s) * HH;

        // one pass: vv = relu(base + avv*w17); stats + pair-packed hi/lo
        short8 Hhi[4], Hlo[4];
        float sm = 0.f, s2 = 0.f;
#pragma unroll
        for (int st = 0; st < 4; st++) {
            const float* p = brow + quad * 8 + 32 * st;
            float4 b0 = *(const float4*)p;
            float4 b1q = *(const float4*)(p + 4);
            float h[8] = {b0.x, b0.y, b0.z, b0.w, b1q.x, b1q.y, b1q.z, b1q.w};
            uint_t hw[4], lw[4];
#pragma unroll
            for (int pr = 0; pr < 4; pr++) {
                float a = fmaxf(fmaf(avv, w17v[st][2 * pr], h[2 * pr]), 0.f);
                float c = fmaxf(fmaf(avv, w17v[st][2 * pr + 1], h[2 * pr + 1]), 0.f);
                sm += a; sm += c;
                s2 = fmaf(a, a, s2);
                s2 = fmaf(c, c, s2);
                pair_split(a, c, hw[pr], lw[pr]);
            }
            Hhi[st] = pack4(hw[0], hw[1], hw[2], hw[3]);
            Hlo[st] = pack4(lw[0], lw[1], lw[2], lw[3]);
        }
        sm += __shfl_xor(sm, 16); sm += __shfl_xor(sm, 32);
        s2 += __shfl_xor(s2, 16); s2 += __shfl_xor(s2, 32);
        float m1 = sm * (1.f / 128.f);
        float r1 = rsqrtf(s2 * (1.f / 128.f) - m1 * m1 + 1e-5f);
        float nm = -m1 * r1;

        // Graw = Wh'^T @ vv
        fx4 G[8];
#pragma unroll
        for (int tile = 0; tile < 8; tile++) G[tile] = (fx4){0.f, 0.f, 0.f, 0.f};
#pragma unroll
        for (int st = 0; st < 4; st++) {
            int koff = quad * 8 + 32 * st;
#pragma unroll
            for (int tile = 0; tile < 8; tile++) {
                int off = (tile * 16 + nl) * HH + (koff ^ (nl * 8));
                short8 ph = *(const short8*)(&Phi[off]);
                short8 pl = *(const short8*)(&Plo[off]);
                G[tile] = __builtin_amdgcn_mfma_f32_16x16x32_bf16(ph, Hhi[st], G[tile], 0, 0, 0);
                G[tile] = __builtin_amdgcn_mfma_f32_16x16x32_bf16(pl, Hhi[st], G[tile], 0, 0, 0);
                G[tile] = __builtin_amdgcn_mfma_f32_16x16x32_bf16(ph, Hlo[st], G[tile], 0, 0, 0);
            }
        }

        // LN1 correction + relu; LN2 stats (in-lane over 32 n + 2 shuffles)
        float sm2 = 0.f, ss2 = 0.f;
#pragma unroll
        for (int tile = 0; tile < 8; tile++) {
            float4 w4 = *(const float4*)(W1sg + tile * 16 + quad * 4);
            float4 c4 = *(const float4*)(cbv + tile * 16 + quad * 4);
            float wa[4] = {w4.x, w4.y, w4.z, w4.w};
            float ca[4] = {c4.x, c4.y, c4.z, c4.w};
#pragma unroll
            for (int r = 0; r < 4; r++) {
                float pre = fmaf(r1, G[tile][r], fmaf(nm, wa[r], ca[r]));
                float h2 = fmaxf(pre, 0.f);
                G[tile][r] = h2;
                sm2 += h2;
                ss2 = fmaf(h2, h2, ss2);
            }
        }
        sm2 += __shfl_xor(sm2, 16); sm2 += __shfl_xor(sm2, 32);
        ss2 += __shfl_xor(ss2, 16); ss2 += __shfl_xor(ss2, 32);
        float mean2 = sm2 * (1.f / 128.f);
        float r2 = rsqrtf(ss2 * (1.f / 128.f) - mean2 * mean2 + 1e-5f);
        float msk = val ? 1.f : 0.f;
        float mr2 = msk * r2;

#pragma unroll
        for (int tile = 0; tile < 8; tile++)
#pragma unroll
            for (int r = 0; r < 4; r++)
                acc1[tile][r] = fmaf(mr2, G[tile][r], acc1[tile][r]);
        c0 += msk;
        c1 = fmaf(mr2, mean2, c1);
    }

    // ---- epilogue: xv = gh*(acc1 - c1) + beh*c0 ;  cross-wave LDS reduce,
    //      then coalesced atomics to PERMUTED rows (row = tmap16[t]) ----
    __syncthreads();                       // Phi/Plo dead; reuse as f32 slab
    float* slab = (float*)PhiPlo;          // [4 waves][16 cols][stride 132]
#pragma unroll
    for (int tile = 0; tile < 8; tile++) {
        float4 g4 = *(const float4*)(ghp + tile * 16 + quad * 4);
        float4 be4 = *(const float4*)(behp + tile * 16 + quad * 4);
        float gv[4] = {g4.x, g4.y, g4.z, g4.w};
        float bv[4] = {be4.x, be4.y, be4.z, be4.w};
#pragma unroll
        for (int r = 0; r < 4; r++) {
            float xv = fmaf(gv[r], acc1[tile][r] - c1, bv[r] * c0);
            slab[(wv * 16 + nl) * 132 + tile * 16 + quad * 4 + r] = xv;
        }
    }
    __syncthreads();
    for (int e = tid; e < 16 * HH; e += 256) {
        int t = e >> 7, n = e & 127;
        float vsum = slab[t * 132 + n] + slab[(16 + t) * 132 + n]
                   + slab[(32 + t) * 132 + n] + slab[(48 + t) * 132 + n];
        atomicAdd(&x0[(b * NN + tmap16[t]) * HH + n], vsum);
    }
}

// ---------------- K5: qkvs via MFMA, 512 blocks (32-col n slices) ---------
// agentp != nullptr (layer 2): q (mat 0) and skip (mat 3) are consumed only
// at row t = agent[b]; waves whose 16-row tile lacks the agent row skip
// those mats entirely (wave-uniform).  K/V (mats 1,2) always full.
template <int IN>
__global__ void __launch_bounds__(256) k_qkvs_mfma(
    const float* x, const ushort_t* Whi, const ushort_t* Wlo,
    const float* b0, const float* b1, const float* b2, const float* b3,
    float* q, float* skipo,
    ushort_t* khi, ushort_t* klo, ushort_t* vThi, ushort_t* vTlo,
    const int* agentp)
{
    const int ST = IN / 32;
    int blk = blockIdx.x;             // 512 = 64 m-blocks * 8 col slices
    int m0 = (blk >> 3) * 64;
    int nsl = blk & 7;                // 32-col slice
    int tid = threadIdx.x;
    int wv = tid >> 6;
    int lane = tid & 63;
    int nl = lane & 15;
    int quad = lane >> 4;
    int row = m0 + wv * 16 + nl;

    short8 Ahi[ST], Alo[ST];
    const float* xrow = x + (long)row * IN;
#pragma unroll
    for (int st = 0; st < ST; st++) {
        const float* p = xrow + quad * 8 + 32 * st;
        float4 a4 = *(const float4*)p;
        float4 b4 = *(const float4*)(p + 4);
        float h[8] = {a4.x, a4.y, a4.z, a4.w, b4.x, b4.y, b4.z, b4.w};
        uint_t hw[4], lw[4];
#pragma unroll
        for (int pr = 0; pr < 4; pr++)
            pair_split(h[2 * pr], h[2 * pr + 1], hw[pr], lw[pr]);
        Ahi[st] = pack4(hw[0], hw[1], hw[2], hw[3]);
        Alo[st] = pack4(lw[0], lw[1], lw[2], lw[3]);
    }

    const float* bs_[4] = {b0, b1, b2, b3};
    int rw0 = m0 + wv * 16;                  // wave's 16-row tile start
    bool agset = (agentp != nullptr);
    int agrow = agset ? agentp[rw0 >> 7] : -1;
    bool havea = agset && ((agrow >> 4) == ((rw0 & 127) >> 4));

#pragma unroll
    for (int mat = 0; mat < 4; mat++) {
        if ((mat == 0 || mat == 3) && agset && !havea) continue;
        const ushort_t* Bh = Whi + (mat * 256 + nsl * 32) * IN;
        const ushort_t* Bl = Wlo + (mat * 256 + nsl * 32) * IN;
        fx4 G[2];
#pragma unroll
        for (int tile = 0; tile < 2; tile++) {
            float bc = bs_[mat][nsl * 32 + tile * 16 + nl];
            G[tile] = (fx4){bc, bc, bc, bc};
        }
#pragma unroll
        for (int st = 0; st < ST; st++) {
            int koff = quad * 8 + 32 * st;
#pragma unroll
            for (int tile = 0; tile < 2; tile++) {
                int off = (tile * 16 + nl) * IN + (koff ^ (nl * 8));
                short8 bh8 = *(const short8*)(Bh + off);
                short8 bl8 = *(const short8*)(Bl + off);
                G[tile] = __builtin_amdgcn_mfma_f32_16x16x32_bf16(Ahi[st], bh8, G[tile], 0, 0, 0);
                G[tile] = __builtin_amdgcn_mfma_f32_16x16x32_bf16(Alo[st], bh8, G[tile], 0, 0, 0);
                G[tile] = __builtin_amdgcn_mfma_f32_16x16x32_bf16(Ahi[st], bl8, G[tile], 0, 0, 0);
            }
        }
        int row0 = m0 + wv * 16 + quad * 4;          // rows r=0..3
        if (mat == 0 || mat == 3) {
            float* om = (mat == 0) ? q : skipo;
#pragma unroll
            for (int tile = 0; tile < 2; tile++)
#pragma unroll
                for (int r = 0; r < 4; r++)
                    om[(row0 + r) * HD + nsl * 32 + tile * 16 + nl] = G[tile][r];
        } else if (mat == 1) {
            // K planes, layout [row=b*128+s][256]
#pragma unroll
            for (int tile = 0; tile < 2; tile++) {
                int col = nsl * 32 + tile * 16 + nl;
#pragma unroll
                for (int r = 0; r < 4; r++) {
                    float gv = G[tile][r];
                    ushort_t hb = f2us_tr(gv);
                    khi[(row0 + r) * HD + col] = hb;
                    klo[(row0 + r) * HD + col] = f2us_tr(gv - us2f(hb));
                }
            }
        } else {
            // vT planes: vT[dg = b*256 + col][128 s], 4 consecutive s packed
            int bb = row0 >> 7;
            int s0 = row0 & 127;
#pragma unroll
            for (int tile = 0; tile < 2; tile++) {
                int col = nsl * 32 + tile * 16 + nl;
                int dg = bb * 256 + col;
                ushort4 h4, l4;
                float g0 = G[tile][0], g1 = G[tile][1], g2 = G[tile][2], g3 = G[tile][3];
                ushort_t h0 = f2us_tr(g0), h1 = f2us_tr(g1), h2 = f2us_tr(g2), h3 = f2us_tr(g3);
                h4.x = h0; h4.y = h1; h4.z = h2; h4.w = h3;
                l4.x = f2us_tr(g0 - us2f(h0));
                l4.y = f2us_tr(g1 - us2f(h1));
                l4.z = f2us_tr(g2 - us2f(h2));
                l4.w = f2us_tr(g3 - us2f(h3));
                *(ushort4*)&vThi[dg * NN + s0] = h4;
                *(ushort4*)&vTlo[dg * NN + s0] = l4;
            }
        }
    }
}

// ---------------- K6: attention via MFMA, 2 waves per (b,h,16-t tile) ------
// wave w: QK^T s-tiles {4w..4w+3}; softmax stats combined via LDS (max is
// exact under any order; den/beta reassociation ~1ulp); PV output-d half.
// agentp==nullptr: layer-1, grid 1024 (b,h,tt), full xout.
// agentp!=nullptr: layer-2, grid 128 (b,h), tt = agent[b]>>4; agent row only,
// written directly to outp (fused gather) -- same math, bit-identical row.
__global__ void __launch_bounds__(128) k_attn_mfma(
    const float* qb, const ushort_t* khi, const ushort_t* klo,
    const ushort_t* vThi, const ushort_t* vTlo,
    const float* adjvT, const float* We, const float* skip, float* xout,
    const int* agentp, float* outp)
{
    __shared__ float aL[16][132];     // alpha C->A round-trip (8.4 KB)
    __shared__ float qeL[16];
    __shared__ float mxL[2][16];
    __shared__ float dnL[2][16];
    __shared__ float ebL[2][16];

    int blk = blockIdx.x;
    int b, h, tt;
    if (agentp == nullptr) {          // 1024 = 32b*4h*8tt
        b = blk >> 5; h = (blk >> 3) & 3; tt = blk & 7;
    } else {                          // 128 = 32b*4h
        b = blk >> 2; h = blk & 3; tt = agentp[b] >> 4;
    }
    int t0 = tt * 16;
    int tid = threadIdx.x;
    int w   = tid >> 6;               // wave 0/1
    int lane = tid & 63;
    int nl = lane & 15;
    int quad = lane >> 4;

    // ---- Q A-frags (split hi/lo) + qe partial (q . we) ----
    short8 Qhi[2], Qlo[2];
    float qe = 0.f;
#pragma unroll
    for (int ks = 0; ks < 2; ks++) {
        const float* p = qb + (b * NN + t0 + nl) * HD + h * DHEAD + quad * 8 + 32 * ks;
        const float* wp = We + h * DHEAD + quad * 8 + 32 * ks;
        float4 a0 = *(const float4*)p;
        float4 a1 = *(const float4*)(p + 4);
        float4 w0 = *(const float4*)wp;
        float4 w1 = *(const float4*)(wp + 4);
        float hv[8] = {a0.x, a0.y, a0.z, a0.w, a1.x, a1.y, a1.z, a1.w};
        float wv8[8] = {w0.x, w0.y, w0.z, w0.w, w1.x, w1.y, w1.z, w1.w};
        uint_t hw[4], lw[4];
#pragma unroll
        for (int pr = 0; pr < 4; pr++) {
            float a = hv[2 * pr], c = hv[2 * pr + 1];
            qe = fmaf(a, wv8[2 * pr], qe);
            qe = fmaf(c, wv8[2 * pr + 1], qe);
            pair_split(a, c, hw[pr], lw[pr]);
        }
        Qhi[ks] = pack4(hw[0], hw[1], hw[2], hw[3]);
        Qlo[ks] = pack4(lw[0], lw[1], lw[2], lw[3]);
    }
    qe += __shfl_xor(qe, 16);
    qe += __shfl_xor(qe, 32);
    if (w == 0 && lane < 16) qeL[lane] = qe;   // qe for t = lane
    __syncthreads();
    float qe_r[4];
#pragma unroll
    for (int r = 0; r < 4; r++) qe_r[r] = qeL[quad * 4 + r];
    float we_d[2];
#pragma unroll
    for (int nt2 = 0; nt2 < 2; nt2++) we_d[nt2] = We[h * DHEAD + (w * 2 + nt2) * 16 + nl];

    // ---- QK^T: wave's 4 s-tiles (global st = w*4 + st') ----
    fx4 S[4];
#pragma unroll
    for (int st = 0; st < 4; st++) S[st] = (fx4){0.f, 0.f, 0.f, 0.f};
#pragma unroll
    for (int ks = 0; ks < 2; ks++) {
#pragma unroll
        for (int st = 0; st < 4; st++) {
            long off = (long)(b * NN + (w * 4 + st) * 16 + nl) * HD + h * DHEAD + quad * 8 + 32 * ks;
            short8 bh8 = *(const short8*)(khi + off);
            short8 bl8 = *(const short8*)(klo + off);
            S[st] = __builtin_amdgcn_mfma_f32_16x16x32_bf16(Qhi[ks], bh8, S[st], 0, 0, 0);
            S[st] = __builtin_amdgcn_mfma_f32_16x16x32_bf16(Qlo[ks], bh8, S[st], 0, 0, 0);
            S[st] = __builtin_amdgcn_mfma_f32_16x16x32_bf16(Qhi[ks], bl8, S[st], 0, 0, 0);
        }
    }

    // ---- masked logits (D-layout: row t = quad*4+r, col s = (w*4+st)*16+nl)
    float av[4][4];
#pragma unroll
    for (int st = 0; st < 4; st++)
#pragma unroll
        for (int r = 0; r < 4; r++)
            av[st][r] = adjvT[(b * NN + t0 + quad * 4 + r) * NN + (w * 4 + st) * 16 + nl];
#pragma unroll
    for (int st = 0; st < 4; st++)
#pragma unroll
        for (int r = 0; r < 4; r++) {
            float a = av[st][r];
            S[st][r] = (a != 0.f) ? (S[st][r] + a * qe_r[r]) * 0.125f : -1e30f;
        }

    // ---- partial row max, combine across waves ----
    float mxp[4];
#pragma unroll
    for (int r = 0; r < 4; r++) {
        float m = S[0][r];
#pragma unroll
        for (int st = 1; st < 4; st++) m = fmaxf(m, S[st][r]);
#pragma unroll
        for (int mm = 1; mm < 16; mm <<= 1) m = fmaxf(m, __shfl_xor(m, mm));
        mxp[r] = m;
    }
    if (nl == 0) {
#pragma unroll
        for (int r = 0; r < 4; r++) mxL[w][quad * 4 + r] = mxp[r];
    }
    __syncthreads();
    float mx[4];
#pragma unroll
    for (int r = 0; r < 4; r++)
        mx[r] = fmaxf(mxL[0][quad * 4 + r], mxL[1][quad * 4 + r]);

    // ---- e = exp(S - mx); partial den & e.av, combine ----
    float dnp[4] = {0.f, 0.f, 0.f, 0.f}, ebp[4] = {0.f, 0.f, 0.f, 0.f};
#pragma unroll
    for (int st = 0; st < 4; st++)
#pragma unroll
        for (int r = 0; r < 4; r++) {
            float e = (av[st][r] != 0.f) ? __expf(S[st][r] - mx[r]) : 0.f;
            S[st][r] = e;
            dnp[r] += e;
            ebp[r] = fmaf(e, av[st][r], ebp[r]);
        }
#pragma unroll
    for (int r = 0; r < 4; r++) {
#pragma unroll
        for (int mm = 1; mm < 16; mm <<= 1) {
            dnp[r] += __shfl_xor(dnp[r], mm);
            ebp[r] += __shfl_xor(ebp[r], mm);
        }
    }
    if (nl == 0) {
#pragma unroll
        for (int r = 0; r < 4; r++) {
            dnL[w][quad * 4 + r] = dnp[r];
            ebL[w][quad * 4 + r] = ebp[r];
        }
    }
    __syncthreads();
    float rden[4], beta[4];
#pragma unroll
    for (int r = 0; r < 4; r++) {
        int row = quad * 4 + r;
        float d = dnL[0][row] + dnL[1][row];
        rden[r] = 1.f / fmaxf(d, 1e-16f);
        beta[r] = (ebL[0][row] + ebL[1][row]) * rden[r];
    }

    // ---- alpha -> aL (wave writes its 64-column half) ----
#pragma unroll
    for (int st = 0; st < 4; st++)
#pragma unroll
        for (int r = 0; r < 4; r++)
            aL[quad * 4 + r][(w * 4 + st) * 16 + nl] = S[st][r] * rden[r];
    __syncthreads();

    // ---- A-frags over full s range ----
    short8 Ah[4];
#pragma unroll
    for (int ks = 0; ks < 4; ks++) {
        const float* p = &aL[nl][quad * 8 + 32 * ks];
        float4 a0 = *(const float4*)p;
        float4 a1 = *(const float4*)(p + 4);
        float hv[8] = {a0.x, a0.y, a0.z, a0.w, a1.x, a1.y, a1.z, a1.w};
        uint_t ww[4];
#pragma unroll
        for (int pr = 0; pr < 4; pr++) ww[pr] = pair_hi(hv[2 * pr], hv[2 * pr + 1]);
        Ah[ks] = pack4(ww[0], ww[1], ww[2], ww[3]);
    }

    // ---- PV: wave's output-d half (nt = w*2 + nt2) ----
    fx4 G[2];
#pragma unroll
    for (int nt2 = 0; nt2 < 2; nt2++) {
        fx4 g;
#pragma unroll
        for (int r = 0; r < 4; r++) g[r] = beta[r] * we_d[nt2];
        G[nt2] = g;
    }
#pragma unroll
    for (int ks = 0; ks < 4; ks++) {
#pragma unroll
        for (int nt2 = 0; nt2 < 2; nt2++) {
            long dg = (long)(b * 256 + h * DHEAD + (w * 2 + nt2) * 16 + nl);
            const short8 vh = *(const short8*)(vThi + dg * NN + quad * 8 + 32 * ks);
            const short8 vl = *(const short8*)(vTlo + dg * NN + quad * 8 + 32 * ks);
            G[nt2] = __builtin_amdgcn_mfma_f32_16x16x32_bf16(Ah[ks], vh, G[nt2], 0, 0, 0);
            G[nt2] = __builtin_amdgcn_mfma_f32_16x16x32_bf16(Ah[ks], vl, G[nt2], 0, 0, 0);
        }
    }

    // ---- epilogue ----
    if (agentp == nullptr) {
        // layer 1: full relu(out + skip) -> xout
#pragma unroll
        for (int nt2 = 0; nt2 < 2; nt2++)
#pragma unroll
            for (int r = 0; r < 4; r++) {
                int gi = (b * NN + t0 + quad * 4 + r) * HD + h * DHEAD + (w * 2 + nt2) * 16 + nl;
                xout[gi] = fmaxf(G[nt2][r] + skip[gi], 0.f);
            }
    } else {
        // layer 2 + fused gather: only the agent row reaches the output
        int ag = agentp[b];
#pragma unroll
        for (int nt2 = 0; nt2 < 2; nt2++)
#pragma unroll
            for (int r = 0; r < 4; r++) {
                int t = t0 + quad * 4 + r;
                if (t == ag) {
                    int d = h * DHEAD + (w * 2 + nt2) * 16 + nl;
                    int gi = (b * NN + t) * HD + d;
                    outp[b * HD + d] = fmaxf(G[nt2][r] + skip[gi], 0.f);
                }
            }
    }
}

// ---------------- launch ----------------
extern "C" void kernel_launch(void* const* d_in, const int* in_sizes, int n_in,
                              void* d_out, int out_size, void* d_ws, size_t ws_size,
                              hipStream_t stream) {
    float* out = (float*)d_out;
    (void)hipGetLastError();

    bool ok = (n_in == 31) && in_sizes[0] == BB * NN * FF && in_sizes[2] == BB * NN * NN
              && in_sizes[5] == (FF + EE + 1) * HH && in_sizes[13] == HH * HD
              && in_sizes[22] == HD * HD && out_size == BB * HD;
    if (!ok) { k_sent<<<32, 256, 0, stream>>>(out, -30000.f); return; }

    const size_t WS_NEED = (size_t)8912896 * 4;
    if (ws_size < WS_NEED) { k_sent<<<32, 256, 0, stream>>>(out, -20000.f); return; }

    const float* nf    = (const float*)d_in[0];
    const int*   et    = (const int*)d_in[1];
    const float* adj   = (const float*)d_in[2];
    const int*   agent = (const int*)d_in[3];
    const float* emb   = (const float*)d_in[4];
    const float* W1    = (const float*)d_in[5];
    const float* b1    = (const float*)d_in[6];
    const float* g1    = (const float*)d_in[7];
    const float* be1   = (const float*)d_in[8];
    const float* Wh    = (const float*)d_in[9];
    const float* bh    = (const float*)d_in[10];
    const float* gh    = (const float*)d_in[11];
    const float* beh   = (const float*)d_in[12];
    const float* Wq1   = (const float*)d_in[13];
    const float* bq1   = (const float*)d_in[14];
    const float* Wk1   = (const float*)d_in[15];
    const float* bk1   = (const float*)d_in[16];
    const float* Wv1   = (const float*)d_in[17];
    const float* bv1   = (const float*)d_in[18];
    const float* We1   = (const float*)d_in[19];
    const float* Ws1   = (const float*)d_in[20];
    const float* bs1   = (const float*)d_in[21];
    const float* Wq2   = (const float*)d_in[22];
    const float* bq2   = (const float*)d_in[23];
    const float* Wk2   = (const float*)d_in[24];
    const float* bk2   = (const float*)d_in[25];
    const float* Wv2   = (const float*)d_in[26];
    const float* bv2   = (const float*)d_in[27];
    const float* We2   = (const float*)d_in[28];
    const float* Ws2   = (const float*)d_in[29];
    const float* bs2   = (const float*)d_in[30];

    float* ws   = (float*)d_ws;
    float* slav = ws;                              // 524288 f region (sl_av)
    float* base = ws + 524288;                     // 524288 f
    float* x0   = base + BB * NN * HH;             // 524288 f
    float* q    = x0 + BB * NN * HH;               // 1048576 f
    float* kreg = q + BB * NN * HD;                // 1048576 f -> khi/klo
    float* vreg = kreg + BB * NN * HD;             // 1048576 f -> vThi/vTlo
    float* skip = vreg + BB * NN * HD;             // 1048576 f
    float* areg = skip + BB * NN * HD;             // 1048576 f -> planes + adjvT + sl_s
    float* x1   = areg + BB * NN * HD;
    float* x2   = x1 + BB * NN * HD;

    // econv prep planes in q region (q first written AFTER econv)
    ushort_t* BhiG = (ushort_t*)q;
    ushort_t* BloG = BhiG + HH * HH;
    float*    W1sW = q + 16384;
    float*    cbW  = q + 16512;
    int*      cnts = (int*)(q + 17024);            // 8192 ints
    int*      tmapG = (int*)(q + 25216);           // 8192 ints (rank -> t)

    // K / vT planes
    ushort_t* khi  = (ushort_t*)kreg;              // 1048576 ush
    ushort_t* klo  = khi + BB * NN * HD;           // 1048576 ush
    ushort_t* vThi = (ushort_t*)vreg;
    ushort_t* vTlo = vThi + BB * NN * HD;

    // qkvs weight planes + adjvT + sl_s in areg (4 MB):
    // planes 1.5 MB + adjvT 2 MB + sl_s 0.5 MB = 4 MB exactly
    ushort_t* WhA = (ushort_t*)areg;               // 4*256*128 ush
    ushort_t* WlA = WhA + 4 * 256 * HH;
    ushort_t* WhB = WlA + 4 * 256 * HH;            // 4*256*256 ush
    ushort_t* WlB = WhB + 4 * 256 * HD;
    float* adjvT  = areg + 393216;                 // 524288 f, past planes
    uchar_t* sl_s = (uchar_t*)(areg + 917504);     // 524288 uchars, tail

    int fail = 0;
    hipError_t e;
#define CHK(stage) do { e = hipGetLastError(); if (e != hipSuccess && fail == 0) fail = (stage); } while (0)

    k_prep_all<<<1856, 256, 0, stream>>>(
        adj, adjvT, sl_s, slav, cnts, tmapG,
        nf, et, emb, W1, b1, base, x0,
        Wh, g1, be1, bh, BhiG, BloG, W1sW, cbW,
        Wq1, Wk1, Wv1, Ws1, WhA, WlA,
        Wq2, Wk2, Wv2, Ws2, WhB, WlB);                                               CHK(1);

    k_econv_mfma<<<512, 256, 0, stream>>>(sl_s, slav, cnts, tmapG, base, W1,
                                          BhiG, BloG, W1sW, cbW, gh, beh, x0);       CHK(2);

    k_qkvs_mfma<HH><<<512, 256, 0, stream>>>(x0, WhA, WlA, bq1, bk1, bv1, bs1,
                                             q, skip, khi, klo, vThi, vTlo,
                                             nullptr);                               CHK(3);
    k_attn_mfma<<<1024, 128, 0, stream>>>(q, khi, klo, vThi, vTlo, adjvT, We1,
                                          skip, x1, nullptr, nullptr);               CHK(4);

    k_qkvs_mfma<HD><<<512, 256, 0, stream>>>(x1, WhB, WlB, bq2, bk2, bv2, bs2,
                                             q, skip, khi, klo, vThi, vTlo,
                                             agent);                                 CHK(5);
    k_attn_mfma<<<128, 128, 0, stream>>>(q, khi, klo, vThi, vTlo, adjvT, We2,
                                         skip, x2, agent, out);                      CHK(6);
#undef CHK

    if (fail != 0)
        k_sent<<<32, 256, 0, stream>>>(out, -(1000.f + 500.f * (float)fail));
}

// Round 13
// 245.295 us; speedup vs baseline: 1.0334x; 1.0334x over previous
//
#include <hip/hip_runtime.h>
#include <hip/hip_bf16.h>

typedef __hip_bfloat16 bf16;
typedef unsigned short ushort_t;
typedef unsigned char uchar_t;
typedef unsigned int uint_t;
typedef __attribute__((ext_vector_type(8))) short short8;
typedef __attribute__((ext_vector_type(4))) float fx4;
typedef __attribute__((ext_vector_type(4))) unsigned int uintx4;

#define BB 32
#define NN 128
#define FF 9
#define EE 8
#define HH 128
#define HD 256
#define NHEAD 4
#define DHEAD 64

__device__ __forceinline__ float us2f(ushort_t u) {
    return __uint_as_float(((unsigned int)u) << 16);
}
// truncation split: hi = trunc16(v), lo = v - hi (lo exact in f32)
__device__ __forceinline__ ushort_t f2us_tr(float f) {
    return (ushort_t)(__float_as_uint(f) >> 16);
}
__device__ __forceinline__ short8 pack4(uint_t w0, uint_t w1, uint_t w2, uint_t w3) {
    uintx4 u = (uintx4){w0, w1, w2, w3};
    return __builtin_bit_cast(short8, u);
}
// pair split: a -> low short of word, c -> high short (bit-identical to
// per-element f2us_tr path: keep = bits & 0xffff0000 == us2f(f2us_tr(x)))
__device__ __forceinline__ void pair_split(float a, float c, uint_t& hw, uint_t& lw) {
    uint_t ua = __float_as_uint(a), uc = __float_as_uint(c);
    uint_t ka = ua & 0xffff0000u, kc = uc & 0xffff0000u;
    float la = a - __uint_as_float(ka);
    float lc = c - __uint_as_float(kc);
    hw = (ua >> 16) | kc;
    lw = (__float_as_uint(la) >> 16) | (__float_as_uint(lc) & 0xffff0000u);
}
__device__ __forceinline__ uint_t pair_hi(float a, float c) {
    return (__float_as_uint(a) >> 16) | (__float_as_uint(c) & 0xffff0000u);
}

__global__ void TransformerConvNet_85315230367963_kernel() {}

__global__ void k_sent(float* out, float val) {
    out[blockIdx.x * 256 + threadIdx.x] = val;
}

// ---------------- K_prep_all: all independent prep work, ONE launch -------
// blocks [0,128):      adjvT + lists + cnts, one (b,chunk) per block
//                      (round-12 had 32 blocks x 4 serial chunks: prep
//                      became the long pole; re-parallelized 4x)
// blocks [128,160):    rank per b (recomputes cnts from adj independently
//                      -> no intra-launch ordering dependency; identical
//                      integers -> identical comparator -> same tmapG)
// blocks [160,1184):   base = src @ W1[:17] + b1          (1024 blocks)
// blocks [1184,1440):  zero x0                            (256 blocks)
// blocks [1440,1472):  Wh' split hi/lo + W1s/cb           (32 blocks)
// blocks [1472,1728):  prepw layer1 (IN=128)              (256 blocks)
// blocks [1728,1984):  prepw layer2 (IN=256)              (256 blocks)
__global__ void __launch_bounds__(256) k_prep_all(
    const float* adj, float* adjvT, uchar_t* sl_s, float* sl_av, int* cnts,
    int* tmapG,
    const float* nf, const int* et, const float* emb, const float* W1,
    const float* b1, float* base, float* x0,
    const float* Wh, const float* g1, const float* be1, const float* bh,
    ushort_t* BhiG, ushort_t* BloG, float* W1s, float* cbv,
    const float* Wq1, const float* Wk1, const float* Wv1, const float* Ws1,
    ushort_t* WhA, ushort_t* WlA,
    const float* Wq2, const float* Wk2, const float* Wv2, const float* Ws2,
    ushort_t* WhB, ushort_t* WlB)
{
    __shared__ float tileF[128 * 33];     // 16.9 KB (section 1a)
    __shared__ int   cntP[512];           // (section 1b) [p][t][sh]
    __shared__ int   combL[256];          // (section 1b) [t][sh]

    int blk = blockIdx.x;
    int tid = threadIdx.x;

    if (blk < 128) {
        // ---- adjvT + ballot-compacted lists + cnts, one (b, 32-t chunk) ----
        int b = blk >> 2, c = blk & 3;
        int wv = tid >> 6, lane = tid & 63;
        int t0c = c * 32;
#pragma unroll
        for (int pass = 0; pass < 16; pass++) {
            int s = pass * 8 + (tid >> 5);
            int tq = tid & 31;
            float a = adj[(b * NN + s) * NN + t0c + tq];
            float av = (a > 0.f && a < 1.0f) ? a : 0.f;
            tileF[s * 33 + tq] = av;
        }
        __syncthreads();
#pragma unroll
        for (int j = 0; j < 16; j++) {
            int u = wv * 16 + j;               // 64 (t,sh) units
            int tq = u >> 1, sh = u & 1;
            int t = t0c + tq;
            int s = sh * 64 + lane;
            float av = tileF[s * 33 + tq];
            adjvT[(b * NN + t) * NN + s] = av;
            unsigned long long mask = __ballot(av != 0.f);
            int key = (b * NN + t) * 2 + sh;
            if (av != 0.f) {
                int pos = __popcll(mask & ((1ull << lane) - 1ull));
                sl_s[key * 64 + pos] = (uchar_t)s;
                sl_av[key * 64 + pos] = av;
            }
            if (lane == 0) {
                cnts[key] = (int)__popcll(mask);
                if (mask == 0ull) { sl_s[key * 64] = 0; sl_av[key * 64] = 0.f; }
            }
        }
    } else if (blk < 160) {
        // ---- rank per b: independent cnt recompute (coalesced) + rank ----
        int b = blk - 128;
        int t = tid & 127, p = tid >> 7;
        int c0 = 0, c1 = 0;
        for (int k = 0; k < 32; k++) {
            float a = adj[(b * NN + (2 * k + p)) * NN + t];
            c0 += (a > 0.f && a < 1.0f) ? 1 : 0;
        }
        for (int k = 32; k < 64; k++) {
            float a = adj[(b * NN + (2 * k + p)) * NN + t];
            c1 += (a > 0.f && a < 1.0f) ? 1 : 0;
        }
        cntP[p * 256 + t * 2 + 0] = c0;
        cntP[p * 256 + t * 2 + 1] = c1;
        __syncthreads();
        int sh = tid >> 7, i = tid & 127;
        int ci = cntP[0 * 256 + i * 2 + sh] + cntP[1 * 256 + i * 2 + sh];
        combL[i * 2 + sh] = ci;
        __syncthreads();
        int rank = 0;
        for (int j = 0; j < 128; j++) {
            int cj = combL[j * 2 + sh];
            rank += (cj > ci) || (cj == ci && j < i);
        }
        tmapG[b * 256 + sh * 128 + rank] = i;
    } else if (blk < 1184) {
        // ---- base rows (4 per block)
        int bblk = blk - 160;
        int c = tid & 127;
#pragma unroll
        for (int rr = 0; rr < 2; rr++) {
            int bs = bblk * 4 + rr * 2 + (tid >> 7);
            int ty = et[bs];
            float acc = b1[c];
            for (int f = 0; f < FF; f++)
                acc += nf[bs * FF + f] * W1[f * HH + c];
            for (int e2 = 0; e2 < EE; e2++)
                acc += emb[ty * EE + e2] * W1[(FF + e2) * HH + c];
            base[bs * HH + c] = acc;
        }
    } else if (blk < 1440) {
        // ---- zero x0 (524288 floats = 131072 float4)
        int zblk = blk - 1184;
        float4* p = (float4*)x0 + zblk * 512 + tid * 2;
        p[0] = (float4){0.f, 0.f, 0.f, 0.f};
        p[1] = (float4){0.f, 0.f, 0.f, 0.f};
    } else if (blk < 1472) {
        // ---- Wh' = g1*Wh split bf16 hi/lo, swizzled; W1s/cb (wave per n)
        int n = (blk - 1440) * 4 + (tid >> 6);
        int t = tid & 63;
        int sw = 8 * (n & 15);
        float s1 = 0.f, s2 = 0.f;
#pragma unroll
        for (int kk = 0; kk < 2; kk++) {
            int k = t + kk * 64;
            float w = Wh[k * HH + n];
            float wp = g1[k] * w;
            ushort_t hb = f2us_tr(wp);
            float lo = wp - us2f(hb);
            BhiG[n * HH + (k ^ sw)] = hb;
            BloG[n * HH + (k ^ sw)] = f2us_tr(lo);
            s1 += wp;
            s2 += be1[k] * w;
        }
        for (int m = 1; m < 64; m <<= 1) {
            s1 += __shfl_xor(s1, m);
            s2 += __shfl_xor(s2, m);
        }
        if (t == 0) { W1s[n] = s1; cbv[n] = s2 + bh[n]; }
    } else if (blk < 1728) {
        // ---- prepw layer 1 (IN = HH), key = (mat,n), wave per key
        int key = (blk - 1472) * 4 + (tid >> 6);
        int lane = tid & 63;
        int mat = key >> 8, n = key & 255;
        const float* W = (mat == 0) ? Wq1 : (mat == 1) ? Wk1 : (mat == 2) ? Wv1 : Ws1;
        ushort_t* hi = WhA + mat * 256 * HH;
        ushort_t* lo = WlA + mat * 256 * HH;
        int sw = 8 * (n & 15);
        for (int k = lane; k < HH; k += 64) {
            float w = W[k * HD + n];
            ushort_t hb = f2us_tr(w);
            float l = w - us2f(hb);
            hi[n * HH + (k ^ sw)] = hb;
            lo[n * HH + (k ^ sw)] = f2us_tr(l);
        }
    } else {
        // ---- prepw layer 2 (IN = HD)
        int key = (blk - 1728) * 4 + (tid >> 6);
        int lane = tid & 63;
        int mat = key >> 8, n = key & 255;
        const float* W = (mat == 0) ? Wq2 : (mat == 1) ? Wk2 : (mat == 2) ? Wv2 : Ws2;
        ushort_t* hi = WhB + mat * 256 * HD;
        ushort_t* lo = WlB + mat * 256 * HD;
        int sw = 8 * (n & 15);
        for (int k = lane; k < HD; k += 64) {
            float w = W[k * HD + n];
            ushort_t hb = f2us_tr(w);
            float l = w - us2f(hb);
            hi[n * HD + (k ^ sw)] = hb;
            lo[n * HD + (k ^ sw)] = f2us_tr(l);
        }
    }
}

// ---------------- K3: embed conv, MFMA, compacted + LENGTH-SORTED lists ----
// (unchanged from round 12: 72.3 us, FETCH 5.84 MB, VGPR 248 -- canary)
__global__ void __launch_bounds__(256) k_econv_mfma(
    const uchar_t* sl_s, const float* sl_av, const int* cnts, const int* tmapG,
    const float* base, const float* W1,
    const ushort_t* BhiG, const ushort_t* BloG,
    const float* W1sg, const float* cbv,
    const float* ghp, const float* behp, float* x0)
{
    __shared__ __align__(16) ushort_t PhiPlo[2 * HH * HH];   // 64 KB
    __shared__ int tmap16[16];                               // rank -> t (tile)
    ushort_t* Phi = PhiPlo;
    ushort_t* Plo = PhiPlo + HH * HH;

    int blk = blockIdx.x;
    int b  = blk >> 4;
    int tt = (blk >> 1) & 7;
    int sh = blk & 1;
    if (b >= BB / 2) tt = 7 - tt;      // complementary tier pairing
    int t0 = tt * 16;
    int tid = threadIdx.x;
    int wv  = tid >> 6;
    int lane = tid & 63;
    int nl = lane & 15;
    int quad = lane >> 4;

    if (tid < 16) tmap16[tid] = tmapG[b * 256 + sh * 128 + t0 + tid];

    {
        const uint4* srcH = (const uint4*)BhiG;
        const uint4* srcL = (const uint4*)BloG;
        uint4* dstH = (uint4*)Phi;
        uint4* dstL = (uint4*)Plo;
        for (int i = tid; i < HH * HH / 8; i += 256) {
            dstH[i] = srcH[i];
            dstL[i] = srcL[i];
        }
    }

    float w17v[4][8];
#pragma unroll
    for (int st = 0; st < 4; st++) {
        const float* p = W1 + 17 * HH + quad * 8 + 32 * st;
        float4 a = *(const float4*)p;
        float4 bq = *(const float4*)(p + 4);
        w17v[st][0] = a.x;  w17v[st][1] = a.y;  w17v[st][2] = a.z;  w17v[st][3] = a.w;
        w17v[st][4] = bq.x; w17v[st][5] = bq.y; w17v[st][6] = bq.z; w17v[st][7] = bq.w;
    }

    __syncthreads();

    int myt = tmap16[nl];               // this lane's column t
    int key = ((b << 7) + myt) * 2 + sh;
    int cnt = cnts[key];
    int q = (cnt + 3) >> 2;              // per-wave chunk
    int mq = q;
#pragma unroll
    for (int m = 1; m < 16; m <<= 1) mq = max(mq, __shfl_xor(mq, m));
    const uchar_t* lst_s = sl_s + key * 64;
    const float*   lst_a = sl_av + key * 64;
    int i0 = wv * q;

    fx4 acc1[8];                 // sum_s mask*r2*h2   (per n, per col)
#pragma unroll
    for (int tile = 0; tile < 8; tile++) acc1[tile] = (fx4){0.f, 0.f, 0.f, 0.f};
    float c0 = 0.f;              // sum_s mask
    float c1 = 0.f;              // sum_s mask*r2*mean2

    for (int i = 0; i < mq; i++) {
        int idx = i0 + i;
        bool val = (i < q) && (idx < cnt);
        int ridx = (idx < cnt) ? idx : (cnt > 0 ? cnt - 1 : 0);
        int s = lst_s[ridx];
        float avv = val ? lst_a[ridx] : 0.f;
        const float* brow = base + (b * NN + s) * HH;

        // one pass: vv = relu(base + avv*w17); stats + pair-packed hi/lo
        short8 Hhi[4], Hlo[4];
        float sm = 0.f, s2 = 0.f;
#pragma unroll
        for (int st = 0; st < 4; st++) {
            const float* p = brow + quad * 8 + 32 * st;
            float4 b0 = *(const float4*)p;
            float4 b1q = *(const float4*)(p + 4);
            float h[8] = {b0.x, b0.y, b0.z, b0.w, b1q.x, b1q.y, b1q.z, b1q.w};
            uint_t hw[4], lw[4];
#pragma unroll
            for (int pr = 0; pr < 4; pr++) {
                float a = fmaxf(fmaf(avv, w17v[st][2 * pr], h[2 * pr]), 0.f);
                float c = fmaxf(fmaf(avv, w17v[st][2 * pr + 1], h[2 * pr + 1]), 0.f);
                sm += a; sm += c;
                s2 = fmaf(a, a, s2);
                s2 = fmaf(c, c, s2);
                pair_split(a, c, hw[pr], lw[pr]);
            }
            Hhi[st] = pack4(hw[0], hw[1], hw[2], hw[3]);
            Hlo[st] = pack4(lw[0], lw[1], lw[2], lw[3]);
        }
        sm += __shfl_xor(sm, 16); sm += __shfl_xor(sm, 32);
        s2 += __shfl_xor(s2, 16); s2 += __shfl_xor(s2, 32);
        float m1 = sm * (1.f / 128.f);
        float r1 = rsqrtf(s2 * (1.f / 128.f) - m1 * m1 + 1e-5f);
        float nm = -m1 * r1;

        // Graw = Wh'^T @ vv
        fx4 G[8];
#pragma unroll
        for (int tile = 0; tile < 8; tile++) G[tile] = (fx4){0.f, 0.f, 0.f, 0.f};
#pragma unroll
        for (int st = 0; st < 4; st++) {
            int koff = quad * 8 + 32 * st;
#pragma unroll
            for (int tile = 0; tile < 8; tile++) {
                int off = (tile * 16 + nl) * HH + (koff ^ (nl * 8));
                short8 ph = *(const short8*)(&Phi[off]);
                short8 pl = *(const short8*)(&Plo[off]);
                G[tile] = __builtin_amdgcn_mfma_f32_16x16x32_bf16(ph, Hhi[st], G[tile], 0, 0, 0);
                G[tile] = __builtin_amdgcn_mfma_f32_16x16x32_bf16(pl, Hhi[st], G[tile], 0, 0, 0);
                G[tile] = __builtin_amdgcn_mfma_f32_16x16x32_bf16(ph, Hlo[st], G[tile], 0, 0, 0);
            }
        }

        // LN1 correction + relu; LN2 stats (in-lane over 32 n + 2 shuffles)
        float sm2 = 0.f, ss2 = 0.f;
#pragma unroll
        for (int tile = 0; tile < 8; tile++) {
            float4 w4 = *(const float4*)(W1sg + tile * 16 + quad * 4);
            float4 c4 = *(const float4*)(cbv + tile * 16 + quad * 4);
            float wa[4] = {w4.x, w4.y, w4.z, w4.w};
            float ca[4] = {c4.x, c4.y, c4.z, c4.w};
#pragma unroll
            for (int r = 0; r < 4; r++) {
                float pre = fmaf(r1, G[tile][r], fmaf(nm, wa[r], ca[r]));
                float h2 = fmaxf(pre, 0.f);
                G[tile][r] = h2;
                sm2 += h2;
                ss2 = fmaf(h2, h2, ss2);
            }
        }
        sm2 += __shfl_xor(sm2, 16); sm2 += __shfl_xor(sm2, 32);
        ss2 += __shfl_xor(ss2, 16); ss2 += __shfl_xor(ss2, 32);
        float mean2 = sm2 * (1.f / 128.f);
        float r2 = rsqrtf(ss2 * (1.f / 128.f) - mean2 * mean2 + 1e-5f);
        float msk = val ? 1.f : 0.f;
        float mr2 = msk * r2;

#pragma unroll
        for (int tile = 0; tile < 8; tile++)
#pragma unroll
            for (int r = 0; r < 4; r++)
                acc1[tile][r] = fmaf(mr2, G[tile][r], acc1[tile][r]);
        c0 += msk;
        c1 = fmaf(mr2, mean2, c1);
    }

    // ---- epilogue: xv = gh*(acc1 - c1) + beh*c0 ;  cross-wave LDS reduce,
    //      then coalesced atomics to PERMUTED rows (row = tmap16[t]) ----
    __syncthreads();                       // Phi/Plo dead; reuse as f32 slab
    float* slab = (float*)PhiPlo;          // [4 waves][16 cols][stride 132]
#pragma unroll
    for (int tile = 0; tile < 8; tile++) {
        float4 g4 = *(const float4*)(ghp + tile * 16 + quad * 4);
        float4 be4 = *(const float4*)(behp + tile * 16 + quad * 4);
        float gv[4] = {g4.x, g4.y, g4.z, g4.w};
        float bv[4] = {be4.x, be4.y, be4.z, be4.w};
#pragma unroll
        for (int r = 0; r < 4; r++) {
            float xv = fmaf(gv[r], acc1[tile][r] - c1, bv[r] * c0);
            slab[(wv * 16 + nl) * 132 + tile * 16 + quad * 4 + r] = xv;
        }
    }
    __syncthreads();
    for (int e = tid; e < 16 * HH; e += 256) {
        int t = e >> 7, n = e & 127;
        float vsum = slab[t * 132 + n] + slab[(16 + t) * 132 + n]
                   + slab[(32 + t) * 132 + n] + slab[(48 + t) * 132 + n];
        atomicAdd(&x0[(b * NN + tmap16[t]) * HH + n], vsum);
    }
}

// ---------------- K5: qkvs via MFMA, 512 blocks (32-col n slices) ---------
// agentp != nullptr (layer 2): q (mat 0) and skip (mat 3) are consumed only
// at row t = agent[b]; waves whose 16-row tile lacks the agent row skip
// those mats entirely (wave-uniform).  K/V (mats 1,2) always full.
template <int IN>
__global__ void __launch_bounds__(256) k_qkvs_mfma(
    const float* x, const ushort_t* Whi, const ushort_t* Wlo,
    const float* b0, const float* b1, const float* b2, const float* b3,
    float* q, float* skipo,
    ushort_t* khi, ushort_t* klo, ushort_t* vThi, ushort_t* vTlo,
    const int* agentp)
{
    const int ST = IN / 32;
    int blk = blockIdx.x;             // 512 = 64 m-blocks * 8 col slices
    int m0 = (blk >> 3) * 64;
    int nsl = blk & 7;                // 32-col slice
    int tid = threadIdx.x;
    int wv = tid >> 6;
    int lane = tid & 63;
    int nl = lane & 15;
    int quad = lane >> 4;
    int row = m0 + wv * 16 + nl;

    short8 Ahi[ST], Alo[ST];
    const float* xrow = x + (long)row * IN;
#pragma unroll
    for (int st = 0; st < ST; st++) {
        const float* p = xrow + quad * 8 + 32 * st;
        float4 a4 = *(const float4*)p;
        float4 b4 = *(const float4*)(p + 4);
        float h[8] = {a4.x, a4.y, a4.z, a4.w, b4.x, b4.y, b4.z, b4.w};
        uint_t hw[4], lw[4];
#pragma unroll
        for (int pr = 0; pr < 4; pr++)
            pair_split(h[2 * pr], h[2 * pr + 1], hw[pr], lw[pr]);
        Ahi[st] = pack4(hw[0], hw[1], hw[2], hw[3]);
        Alo[st] = pack4(lw[0], lw[1], lw[2], lw[3]);
    }

    const float* bs_[4] = {b0, b1, b2, b3};
    int rw0 = m0 + wv * 16;                  // wave's 16-row tile start
    bool agset = (agentp != nullptr);
    int agrow = agset ? agentp[rw0 >> 7] : -1;
    bool havea = agset && ((agrow >> 4) == ((rw0 & 127) >> 4));

#pragma unroll
    for (int mat = 0; mat < 4; mat++) {
        if ((mat == 0 || mat == 3) && agset && !havea) continue;
        const ushort_t* Bh = Whi + (mat * 256 + nsl * 32) * IN;
        const ushort_t* Bl = Wlo + (mat * 256 + nsl * 32) * IN;
        fx4 G[2];
#pragma unroll
        for (int tile = 0; tile < 2; tile++) {
            float bc = bs_[mat][nsl * 32 + tile * 16 + nl];
            G[tile] = (fx4){bc, bc, bc, bc};
        }
#pragma unroll
        for (int st = 0; st < ST; st++) {
            int koff = quad * 8 + 32 * st;
#pragma unroll
            for (int tile = 0; tile < 2; tile++) {
                int off = (tile * 16 + nl) * IN + (koff ^ (nl * 8));
                short8 bh8 = *(const short8*)(Bh + off);
                short8 bl8 = *(const short8*)(Bl + off);
                G[tile] = __builtin_amdgcn_mfma_f32_16x16x32_bf16(Ahi[st], bh8, G[tile], 0, 0, 0);
                G[tile] = __builtin_amdgcn_mfma_f32_16x16x32_bf16(Alo[st], bh8, G[tile], 0, 0, 0);
                G[tile] = __builtin_amdgcn_mfma_f32_16x16x32_bf16(Ahi[st], bl8, G[tile], 0, 0, 0);
            }
        }
        int row0 = m0 + wv * 16 + quad * 4;          // rows r=0..3
        if (mat == 0 || mat == 3) {
            float* om = (mat == 0) ? q : skipo;
#pragma unroll
            for (int tile = 0; tile < 2; tile++)
#pragma unroll
                for (int r = 0; r < 4; r++)
                    om[(row0 + r) * HD + nsl * 32 + tile * 16 + nl] = G[tile][r];
        } else if (mat == 1) {
            // K planes, layout [row=b*128+s][256]
#pragma unroll
            for (int tile = 0; tile < 2; tile++) {
                int col = nsl * 32 + tile * 16 + nl;
#pragma unroll
                for (int r = 0; r < 4; r++) {
                    float gv = G[tile][r];
                    ushort_t hb = f2us_tr(gv);
                    khi[(row0 + r) * HD + col] = hb;
                    klo[(row0 + r) * HD + col] = f2us_tr(gv - us2f(hb));
                }
            }
        } else {
            // vT planes: vT[dg = b*256 + col][128 s], 4 consecutive s packed
            int bb = row0 >> 7;
            int s0 = row0 & 127;
#pragma unroll
            for (int tile = 0; tile < 2; tile++) {
                int col = nsl * 32 + tile * 16 + nl;
                int dg = bb * 256 + col;
                ushort4 h4, l4;
                float g0 = G[tile][0], g1 = G[tile][1], g2 = G[tile][2], g3 = G[tile][3];
                ushort_t h0 = f2us_tr(g0), h1 = f2us_tr(g1), h2 = f2us_tr(g2), h3 = f2us_tr(g3);
                h4.x = h0; h4.y = h1; h4.z = h2; h4.w = h3;
                l4.x = f2us_tr(g0 - us2f(h0));
                l4.y = f2us_tr(g1 - us2f(h1));
                l4.z = f2us_tr(g2 - us2f(h2));
                l4.w = f2us_tr(g3 - us2f(h3));
                *(ushort4*)&vThi[dg * NN + s0] = h4;
                *(ushort4*)&vTlo[dg * NN + s0] = l4;
            }
        }
    }
}

// ---------------- K6: attention via MFMA, 4 waves per (b,h,16-t tile) ------
// wave w: QK^T s-tiles {2w,2w+1}; softmax stats combined via LDS [4][16]
// (max exact; den/beta reassociation ~1ulp -- round-7 precedent); PV
// output-d quarter nt = w.  agentp==nullptr: layer-1, grid 1024, full xout.
// agentp!=nullptr: layer-2, grid 128, tt = agent[b]>>4, fused gather.
__global__ void __launch_bounds__(256) k_attn_mfma(
    const float* qb, const ushort_t* khi, const ushort_t* klo,
    const ushort_t* vThi, const ushort_t* vTlo,
    const float* adjvT, const float* We, const float* skip, float* xout,
    const int* agentp, float* outp)
{
    __shared__ float aL[16][132];     // alpha C->A round-trip (8.4 KB)
    __shared__ float qeL[16];
    __shared__ float mxL[4][16];
    __shared__ float dnL[4][16];
    __shared__ float ebL[4][16];

    int blk = blockIdx.x;
    int b, h, tt;
    if (agentp == nullptr) {          // 1024 = 32b*4h*8tt
        b = blk >> 5; h = (blk >> 3) & 3; tt = blk & 7;
    } else {                          // 128 = 32b*4h
        b = blk >> 2; h = blk & 3; tt = agentp[b] >> 4;
    }
    int t0 = tt * 16;
    int tid = threadIdx.x;
    int w   = tid >> 6;               // wave 0..3
    int lane = tid & 63;
    int nl = lane & 15;
    int quad = lane >> 4;

    // ---- Q A-frags (split hi/lo) + qe partial (q . we) ----
    short8 Qhi[2], Qlo[2];
    float qe = 0.f;
#pragma unroll
    for (int ks = 0; ks < 2; ks++) {
        const float* p = qb + (b * NN + t0 + nl) * HD + h * DHEAD + quad * 8 + 32 * ks;
        const float* wp = We + h * DHEAD + quad * 8 + 32 * ks;
        float4 a0 = *(const float4*)p;
        float4 a1 = *(const float4*)(p + 4);
        float4 w0 = *(const float4*)wp;
        float4 w1 = *(const float4*)(wp + 4);
        float hv[8] = {a0.x, a0.y, a0.z, a0.w, a1.x, a1.y, a1.z, a1.w};
        float wv8[8] = {w0.x, w0.y, w0.z, w0.w, w1.x, w1.y, w1.z, w1.w};
        uint_t hw[4], lw[4];
#pragma unroll
        for (int pr = 0; pr < 4; pr++) {
            float a = hv[2 * pr], c = hv[2 * pr + 1];
            qe = fmaf(a, wv8[2 * pr], qe);
            qe = fmaf(c, wv8[2 * pr + 1], qe);
            pair_split(a, c, hw[pr], lw[pr]);
        }
        Qhi[ks] = pack4(hw[0], hw[1], hw[2], hw[3]);
        Qlo[ks] = pack4(lw[0], lw[1], lw[2], lw[3]);
    }
    qe += __shfl_xor(qe, 16);
    qe += __shfl_xor(qe, 32);
    if (w == 0 && lane < 16) qeL[lane] = qe;   // qe for t = lane
    __syncthreads();
    float qe_r[4];
#pragma unroll
    for (int r = 0; r < 4; r++) qe_r[r] = qeL[quad * 4 + r];
    float we_dv = We[h * DHEAD + w * 16 + nl];

    // ---- QK^T: wave's 2 s-tiles (global st = w*2 + st') ----
    fx4 S[2];
#pragma unroll
    for (int st = 0; st < 2; st++) S[st] = (fx4){0.f, 0.f, 0.f, 0.f};
#pragma unroll
    for (int ks = 0; ks < 2; ks++) {
#pragma unroll
        for (int st = 0; st < 2; st++) {
            long off = (long)(b * NN + (w * 2 + st) * 16 + nl) * HD + h * DHEAD + quad * 8 + 32 * ks;
            short8 bh8 = *(const short8*)(khi + off);
            short8 bl8 = *(const short8*)(klo + off);
            S[st] = __builtin_amdgcn_mfma_f32_16x16x32_bf16(Qhi[ks], bh8, S[st], 0, 0, 0);
            S[st] = __builtin_amdgcn_mfma_f32_16x16x32_bf16(Qlo[ks], bh8, S[st], 0, 0, 0);
            S[st] = __builtin_amdgcn_mfma_f32_16x16x32_bf16(Qhi[ks], bl8, S[st], 0, 0, 0);
        }
    }

    // ---- masked logits (D-layout: row t = quad*4+r, col s = (w*2+st)*16+nl)
    float av[2][4];
#pragma unroll
    for (int st = 0; st < 2; st++)
#pragma unroll
        for (int r = 0; r < 4; r++)
            av[st][r] = adjvT[(b * NN + t0 + quad * 4 + r) * NN + (w * 2 + st) * 16 + nl];
#pragma unroll
    for (int st = 0; st < 2; st++)
#pragma unroll
        for (int r = 0; r < 4; r++) {
            float a = av[st][r];
            S[st][r] = (a != 0.f) ? (S[st][r] + a * qe_r[r]) * 0.125f : -1e30f;
        }

    // ---- partial row max, combine across 4 waves ----
    float mxp[4];
#pragma unroll
    for (int r = 0; r < 4; r++) {
        float m = fmaxf(S[0][r], S[1][r]);
#pragma unroll
        for (int mm = 1; mm < 16; mm <<= 1) m = fmaxf(m, __shfl_xor(m, mm));
        mxp[r] = m;
    }
    if (nl == 0) {
#pragma unroll
        for (int r = 0; r < 4; r++) mxL[w][quad * 4 + r] = mxp[r];
    }
    __syncthreads();
    float mx[4];
#pragma unroll
    for (int r = 0; r < 4; r++) {
        int row = quad * 4 + r;
        mx[r] = fmaxf(fmaxf(mxL[0][row], mxL[1][row]),
                      fmaxf(mxL[2][row], mxL[3][row]));
    }

    // ---- e = exp(S - mx); partial den & e.av, combine ----
    float dnp[4] = {0.f, 0.f, 0.f, 0.f}, ebp[4] = {0.f, 0.f, 0.f, 0.f};
#pragma unroll
    for (int st = 0; st < 2; st++)
#pragma unroll
        for (int r = 0; r < 4; r++) {
            float e = (av[st][r] != 0.f) ? __expf(S[st][r] - mx[r]) : 0.f;
            S[st][r] = e;
            dnp[r] += e;
            ebp[r] = fmaf(e, av[st][r], ebp[r]);
        }
#pragma unroll
    for (int r = 0; r < 4; r++) {
#pragma unroll
        for (int mm = 1; mm < 16; mm <<= 1) {
            dnp[r] += __shfl_xor(dnp[r], mm);
            ebp[r] += __shfl_xor(ebp[r], mm);
        }
    }
    if (nl == 0) {
#pragma unroll
        for (int r = 0; r < 4; r++) {
            dnL[w][quad * 4 + r] = dnp[r];
            ebL[w][quad * 4 + r] = ebp[r];
        }
    }
    __syncthreads();
    float rden[4], beta[4];
#pragma unroll
    for (int r = 0; r < 4; r++) {
        int row = quad * 4 + r;
        float d = ((dnL[0][row] + dnL[1][row]) + dnL[2][row]) + dnL[3][row];
        rden[r] = 1.f / fmaxf(d, 1e-16f);
        beta[r] = (((ebL[0][row] + ebL[1][row]) + ebL[2][row]) + ebL[3][row]) * rden[r];
    }

    // ---- alpha -> aL (wave writes its 32-column slice) ----
#pragma unroll
    for (int st = 0; st < 2; st++)
#pragma unroll
        for (int r = 0; r < 4; r++)
            aL[quad * 4 + r][(w * 2 + st) * 16 + nl] = S[st][r] * rden[r];
    __syncthreads();

    // ---- A-frags over full s range ----
    short8 Ah[4];
#pragma unroll
    for (int ks = 0; ks < 4; ks++) {
        const float* p = &aL[nl][quad * 8 + 32 * ks];
        float4 a0 = *(const float4*)p;
        float4 a1 = *(const float4*)(p + 4);
        float hv[8] = {a0.x, a0.y, a0.z, a0.w, a1.x, a1.y, a1.z, a1.w};
        uint_t ww[4];
#pragma unroll
        for (int pr = 0; pr < 4; pr++) ww[pr] = pair_hi(hv[2 * pr], hv[2 * pr + 1]);
        Ah[ks] = pack4(ww[0], ww[1], ww[2], ww[3]);
    }

    // ---- PV: wave's output-d quarter (nt = w) ----
    fx4 G;
#pragma unroll
    for (int r = 0; r < 4; r++) G[r] = beta[r] * we_dv;
    {
        long dg = (long)(b * 256 + h * DHEAD + w * 16 + nl);
        const ushort_t* vhB = vThi + dg * NN;
        const ushort_t* vlB = vTlo + dg * NN;
#pragma unroll
        for (int ks = 0; ks < 4; ks++) {
            const short8 vh = *(const short8*)(vhB + quad * 8 + 32 * ks);
            const short8 vl = *(const short8*)(vlB + quad * 8 + 32 * ks);
            G = __builtin_amdgcn_mfma_f32_16x16x32_bf16(Ah[ks], vh, G, 0, 0, 0);
            G = __builtin_amdgcn_mfma_f32_16x16x32_bf16(Ah[ks], vl, G, 0, 0, 0);
        }
    }

    // ---- epilogue ----
    if (agentp == nullptr) {
        // layer 1: full relu(out + skip) -> xout
#pragma unroll
        for (int r = 0; r < 4; r++) {
            int gi = (b * NN + t0 + quad * 4 + r) * HD + h * DHEAD + w * 16 + nl;
            xout[gi] = fmaxf(G[r] + skip[gi], 0.f);
        }
    } else {
        // layer 2 + fused gather: only the agent row reaches the output
        int ag = agentp[b];
#pragma unroll
        for (int r = 0; r < 4; r++) {
            int t = t0 + quad * 4 + r;
            if (t == ag) {
                int d = h * DHEAD + w * 16 + nl;
                int gi = (b * NN + t) * HD + d;
                outp[b * HD + d] = fmaxf(G[r] + skip[gi], 0.f);
            }
        }
    }
}

// ---------------- launch ----------------
extern "C" void kernel_launch(void* const* d_in, const int* in_sizes, int n_in,
                              void* d_out, int out_size, void* d_ws, size_t ws_size,
                              hipStream_t stream) {
    float* out = (float*)d_out;
    (void)hipGetLastError();

    bool ok = (n_in == 31) && in_sizes[0] == BB * NN * FF && in_sizes[2] == BB * NN * NN
              && in_sizes[5] == (FF + EE + 1) * HH && in_sizes[13] == HH * HD
              && in_sizes[22] == HD * HD && out_size == BB * HD;
    if (!ok) { k_sent<<<32, 256, 0, stream>>>(out, -30000.f); return; }

    const size_t WS_NEED = (size_t)8912896 * 4;
    if (ws_size < WS_NEED) { k_sent<<<32, 256, 0, stream>>>(out, -20000.f); return; }

    const float* nf    = (const float*)d_in[0];
    const int*   et    = (const int*)d_in[1];
    const float* adj   = (const float*)d_in[2];
    const int*   agent = (const int*)d_in[3];
    const float* emb   = (const float*)d_in[4];
    const float* W1    = (const float*)d_in[5];
    const float* b1    = (const float*)d_in[6];
    const float* g1    = (const float*)d_in[7];
    const float* be1   = (const float*)d_in[8];
    const float* Wh    = (const float*)d_in[9];
    const float* bh    = (const float*)d_in[10];
    const float* gh    = (const float*)d_in[11];
    const float* beh   = (const float*)d_in[12];
    const float* Wq1   = (const float*)d_in[13];
    const float* bq1   = (const float*)d_in[14];
    const float* Wk1   = (const float*)d_in[15];
    const float* bk1   = (const float*)d_in[16];
    const float* Wv1   = (const float*)d_in[17];
    const float* bv1   = (const float*)d_in[18];
    const float* We1   = (const float*)d_in[19];
    const float* Ws1   = (const float*)d_in[20];
    const float* bs1   = (const float*)d_in[21];
    const float* Wq2   = (const float*)d_in[22];
    const float* bq2   = (const float*)d_in[23];
    const float* Wk2   = (const float*)d_in[24];
    const float* bk2   = (const float*)d_in[25];
    const float* Wv2   = (const float*)d_in[26];
    const float* bv2   = (const float*)d_in[27];
    const float* We2   = (const float*)d_in[28];
    const float* Ws2   = (const float*)d_in[29];
    const float* bs2   = (const float*)d_in[30];

    float* ws   = (float*)d_ws;
    float* slav = ws;                              // 524288 f region (sl_av)
    float* base = ws + 524288;                     // 524288 f
    float* x0   = base + BB * NN * HH;             // 524288 f
    float* q    = x0 + BB * NN * HH;               // 1048576 f
    float* kreg = q + BB * NN * HD;                // 1048576 f -> khi/klo
    float* vreg = kreg + BB * NN * HD;             // 1048576 f -> vThi/vTlo
    float* skip = vreg + BB * NN * HD;             // 1048576 f
    float* areg = skip + BB * NN * HD;             // 1048576 f -> planes + adjvT + sl_s
    float* x1   = areg + BB * NN * HD;
    float* x2   = x1 + BB * NN * HD;

    // econv prep planes in q region (q first written AFTER econv)
    ushort_t* BhiG = (ushort_t*)q;
    ushort_t* BloG = BhiG + HH * HH;
    float*    W1sW = q + 16384;
    float*    cbW  = q + 16512;
    int*      cnts = (int*)(q + 17024);            // 8192 ints
    int*      tmapG = (int*)(q + 25216);           // 8192 ints (rank -> t)

    // K / vT planes
    ushort_t* khi  = (ushort_t*)kreg;              // 1048576 ush
    ushort_t* klo  = khi + BB * NN * HD;           // 1048576 ush
    ushort_t* vThi = (ushort_t*)vreg;
    ushort_t* vTlo = vThi + BB * NN * HD;

    // qkvs weight planes + adjvT + sl_s in areg (4 MB):
    // planes 1.5 MB + adjvT 2 MB + sl_s 0.5 MB = 4 MB exactly
    ushort_t* WhA = (ushort_t*)areg;               // 4*256*128 ush
    ushort_t* WlA = WhA + 4 * 256 * HH;
    ushort_t* WhB = WlA + 4 * 256 * HH;            // 4*256*256 ush
    ushort_t* WlB = WhB + 4 * 256 * HD;
    float* adjvT  = areg + 393216;                 // 524288 f, past planes
    uchar_t* sl_s = (uchar_t*)(areg + 917504);     // 524288 uchars, tail

    int fail = 0;
    hipError_t e;
#define CHK(stage) do { e = hipGetLastError(); if (e != hipSuccess && fail == 0) fail = (stage); } while (0)

    k_prep_all<<<1984, 256, 0, stream>>>(
        adj, adjvT, sl_s, slav, cnts, tmapG,
        nf, et, emb, W1, b1, base, x0,
        Wh, g1, be1, bh, BhiG, BloG, W1sW, cbW,
        Wq1, Wk1, Wv1, Ws1, WhA, WlA,
        Wq2, Wk2, Wv2, Ws2, WhB, WlB);                                               CHK(1);

    k_econv_mfma<<<512, 256, 0, stream>>>(sl_s, slav, cnts, tmapG, base, W1,
                                          BhiG, BloG, W1sW, cbW, gh, beh, x0);       CHK(2);

    k_qkvs_mfma<HH><<<512, 256, 0, stream>>>(x0, WhA, WlA, bq1, bk1, bv1, bs1,
                                             q, skip, khi, klo, vThi, vTlo,
                                             nullptr);                               CHK(3);
    k_attn_mfma<<<1024, 256, 0, stream>>>(q, khi, klo, vThi, vTlo, adjvT, We1,
                                          skip, x1, nullptr, nullptr);               CHK(4);

    k_qkvs_mfma<HD><<<512, 256, 0, stream>>>(x1, WhB, WlB, bq2, bk2, bv2, bs2,
                                             q, skip, khi, klo, vThi, vTlo,
                                             agent);                                 CHK(5);
    k_attn_mfma<<<128, 256, 0, stream>>>(q, khi, klo, vThi, vTlo, adjvT, We2,
                                         skip, x2, agent, out);                      CHK(6);
#undef CHK

    if (fail != 0)
        k_sent<<<32, 256, 0, stream>>>(out, -(1000.f + 500.f * (float)fail));
}

// Round 14
// 240.339 us; speedup vs baseline: 1.0547x; 1.0206x over previous
//
#include <hip/hip_runtime.h>
#include <hip/hip_bf16.h>

typedef __hip_bfloat16 bf16;
typedef unsigned short ushort_t;
typedef unsigned char uchar_t;
typedef unsigned int uint_t;
typedef __attribute__((ext_vector_type(8))) short short8;
typedef __attribute__((ext_vector_type(4))) float fx4;
typedef __attribute__((ext_vector_type(4))) unsigned int uintx4;

#define BB 32
#define NN 128
#define FF 9
#define EE 8
#define HH 128
#define HD 256
#define NHEAD 4
#define DHEAD 64

__device__ __forceinline__ float us2f(ushort_t u) {
    return __uint_as_float(((unsigned int)u) << 16);
}
// truncation split: hi = trunc16(v), lo = v - hi (lo exact in f32)
__device__ __forceinline__ ushort_t f2us_tr(float f) {
    return (ushort_t)(__float_as_uint(f) >> 16);
}
__device__ __forceinline__ short8 pack4(uint_t w0, uint_t w1, uint_t w2, uint_t w3) {
    uintx4 u = (uintx4){w0, w1, w2, w3};
    return __builtin_bit_cast(short8, u);
}
// pair split: a -> low short of word, c -> high short (bit-identical to
// per-element f2us_tr path: keep = bits & 0xffff0000 == us2f(f2us_tr(x)))
__device__ __forceinline__ void pair_split(float a, float c, uint_t& hw, uint_t& lw) {
    uint_t ua = __float_as_uint(a), uc = __float_as_uint(c);
    uint_t ka = ua & 0xffff0000u, kc = uc & 0xffff0000u;
    float la = a - __uint_as_float(ka);
    float lc = c - __uint_as_float(kc);
    hw = (ua >> 16) | kc;
    lw = (__float_as_uint(la) >> 16) | (__float_as_uint(lc) & 0xffff0000u);
}
__device__ __forceinline__ uint_t pair_hi(float a, float c) {
    return (__float_as_uint(a) >> 16) | (__float_as_uint(c) & 0xffff0000u);
}

__global__ void TransformerConvNet_85315230367963_kernel() {}

__global__ void k_sent(float* out, float val) {
    out[blockIdx.x * 256 + threadIdx.x] = val;
}

// ---------------- K_prep_all: all independent prep work, ONE launch -------
// blocks [0,128):      adjvT + lists + cnts, one (b,chunk) per block
// blocks [128,160):    rank per b (independent cnt recompute -> tmapG)
// blocks [160,1184):   base = src @ W1[:17] + b1          (1024 blocks)
// blocks [1184,1440):  zero x0                            (256 blocks)
// blocks [1440,1472):  Wh' split hi/lo + W1s/cb           (32 blocks)
// blocks [1472,1728):  prepw layer1 (IN=128)              (256 blocks)
// blocks [1728,1984):  prepw layer2 (IN=256)              (256 blocks)
__global__ void __launch_bounds__(256) k_prep_all(
    const float* adj, float* adjvT, uchar_t* sl_s, float* sl_av, int* cnts,
    int* tmapG,
    const float* nf, const int* et, const float* emb, const float* W1,
    const float* b1, float* base, float* x0,
    const float* Wh, const float* g1, const float* be1, const float* bh,
    ushort_t* BhiG, ushort_t* BloG, float* W1s, float* cbv,
    const float* Wq1, const float* Wk1, const float* Wv1, const float* Ws1,
    ushort_t* WhA, ushort_t* WlA,
    const float* Wq2, const float* Wk2, const float* Wv2, const float* Ws2,
    ushort_t* WhB, ushort_t* WlB)
{
    __shared__ float tileF[128 * 33];     // 16.9 KB (section 1a)
    __shared__ int   cntP[512];           // (section 1b) [p][t][sh]
    __shared__ int   combL[256];          // (section 1b) [t][sh]

    int blk = blockIdx.x;
    int tid = threadIdx.x;

    if (blk < 128) {
        // ---- adjvT + ballot-compacted lists + cnts, one (b, 32-t chunk) ----
        int b = blk >> 2, c = blk & 3;
        int wv = tid >> 6, lane = tid & 63;
        int t0c = c * 32;
#pragma unroll
        for (int pass = 0; pass < 16; pass++) {
            int s = pass * 8 + (tid >> 5);
            int tq = tid & 31;
            float a = adj[(b * NN + s) * NN + t0c + tq];
            float av = (a > 0.f && a < 1.0f) ? a : 0.f;
            tileF[s * 33 + tq] = av;
        }
        __syncthreads();
#pragma unroll
        for (int j = 0; j < 16; j++) {
            int u = wv * 16 + j;               // 64 (t,sh) units
            int tq = u >> 1, sh = u & 1;
            int t = t0c + tq;
            int s = sh * 64 + lane;
            float av = tileF[s * 33 + tq];
            adjvT[(b * NN + t) * NN + s] = av;
            unsigned long long mask = __ballot(av != 0.f);
            int key = (b * NN + t) * 2 + sh;
            if (av != 0.f) {
                int pos = __popcll(mask & ((1ull << lane) - 1ull));
                sl_s[key * 64 + pos] = (uchar_t)s;
                sl_av[key * 64 + pos] = av;
            }
            if (lane == 0) {
                cnts[key] = (int)__popcll(mask);
                if (mask == 0ull) { sl_s[key * 64] = 0; sl_av[key * 64] = 0.f; }
            }
        }
    } else if (blk < 160) {
        // ---- rank per b: independent cnt recompute (coalesced) + rank ----
        int b = blk - 128;
        int t = tid & 127, p = tid >> 7;
        int c0 = 0, c1 = 0;
        for (int k = 0; k < 32; k++) {
            float a = adj[(b * NN + (2 * k + p)) * NN + t];
            c0 += (a > 0.f && a < 1.0f) ? 1 : 0;
        }
        for (int k = 32; k < 64; k++) {
            float a = adj[(b * NN + (2 * k + p)) * NN + t];
            c1 += (a > 0.f && a < 1.0f) ? 1 : 0;
        }
        cntP[p * 256 + t * 2 + 0] = c0;
        cntP[p * 256 + t * 2 + 1] = c1;
        __syncthreads();
        int sh = tid >> 7, i = tid & 127;
        int ci = cntP[0 * 256 + i * 2 + sh] + cntP[1 * 256 + i * 2 + sh];
        combL[i * 2 + sh] = ci;
        __syncthreads();
        int rank = 0;
        for (int j = 0; j < 128; j++) {
            int cj = combL[j * 2 + sh];
            rank += (cj > ci) || (cj == ci && j < i);
        }
        tmapG[b * 256 + sh * 128 + rank] = i;
    } else if (blk < 1184) {
        // ---- base rows (4 per block)
        int bblk = blk - 160;
        int c = tid & 127;
#pragma unroll
        for (int rr = 0; rr < 2; rr++) {
            int bs = bblk * 4 + rr * 2 + (tid >> 7);
            int ty = et[bs];
            float acc = b1[c];
            for (int f = 0; f < FF; f++)
                acc += nf[bs * FF + f] * W1[f * HH + c];
            for (int e2 = 0; e2 < EE; e2++)
                acc += emb[ty * EE + e2] * W1[(FF + e2) * HH + c];
            base[bs * HH + c] = acc;
        }
    } else if (blk < 1440) {
        // ---- zero x0 (524288 floats = 131072 float4)
        int zblk = blk - 1184;
        float4* p = (float4*)x0 + zblk * 512 + tid * 2;
        p[0] = (float4){0.f, 0.f, 0.f, 0.f};
        p[1] = (float4){0.f, 0.f, 0.f, 0.f};
    } else if (blk < 1472) {
        // ---- Wh' = g1*Wh split bf16 hi/lo, swizzled; W1s/cb (wave per n)
        int n = (blk - 1440) * 4 + (tid >> 6);
        int t = tid & 63;
        int sw = 8 * (n & 15);
        float s1 = 0.f, s2 = 0.f;
#pragma unroll
        for (int kk = 0; kk < 2; kk++) {
            int k = t + kk * 64;
            float w = Wh[k * HH + n];
            float wp = g1[k] * w;
            ushort_t hb = f2us_tr(wp);
            float lo = wp - us2f(hb);
            BhiG[n * HH + (k ^ sw)] = hb;
            BloG[n * HH + (k ^ sw)] = f2us_tr(lo);
            s1 += wp;
            s2 += be1[k] * w;
        }
        for (int m = 1; m < 64; m <<= 1) {
            s1 += __shfl_xor(s1, m);
            s2 += __shfl_xor(s2, m);
        }
        if (t == 0) { W1s[n] = s1; cbv[n] = s2 + bh[n]; }
    } else if (blk < 1728) {
        // ---- prepw layer 1 (IN = HH), key = (mat,n), wave per key
        int key = (blk - 1472) * 4 + (tid >> 6);
        int lane = tid & 63;
        int mat = key >> 8, n = key & 255;
        const float* W = (mat == 0) ? Wq1 : (mat == 1) ? Wk1 : (mat == 2) ? Wv1 : Ws1;
        ushort_t* hi = WhA + mat * 256 * HH;
        ushort_t* lo = WlA + mat * 256 * HH;
        int sw = 8 * (n & 15);
        for (int k = lane; k < HH; k += 64) {
            float w = W[k * HD + n];
            ushort_t hb = f2us_tr(w);
            float l = w - us2f(hb);
            hi[n * HH + (k ^ sw)] = hb;
            lo[n * HH + (k ^ sw)] = f2us_tr(l);
        }
    } else {
        // ---- prepw layer 2 (IN = HD)
        int key = (blk - 1728) * 4 + (tid >> 6);
        int lane = tid & 63;
        int mat = key >> 8, n = key & 255;
        const float* W = (mat == 0) ? Wq2 : (mat == 1) ? Wk2 : (mat == 2) ? Wv2 : Ws2;
        ushort_t* hi = WhB + mat * 256 * HD;
        ushort_t* lo = WlB + mat * 256 * HD;
        int sw = 8 * (n & 15);
        for (int k = lane; k < HD; k += 64) {
            float w = W[k * HD + n];
            ushort_t hb = f2us_tr(w);
            float l = w - us2f(hb);
            hi[n * HD + (k ^ sw)] = hb;
            lo[n * HD + (k ^ sw)] = f2us_tr(l);
        }
    }
}

// ---------------- K3: embed conv, MFMA, compacted + LENGTH-SORTED lists ----
// (unchanged: 72.3 us, FETCH 5.85 MB, VGPR 248 -- canary)
__global__ void __launch_bounds__(256) k_econv_mfma(
    const uchar_t* sl_s, const float* sl_av, const int* cnts, const int* tmapG,
    const float* base, const float* W1,
    const ushort_t* BhiG, const ushort_t* BloG,
    const float* W1sg, const float* cbv,
    const float* ghp, const float* behp, float* x0)
{
    __shared__ __align__(16) ushort_t PhiPlo[2 * HH * HH];   // 64 KB
    __shared__ int tmap16[16];                               // rank -> t (tile)
    ushort_t* Phi = PhiPlo;
    ushort_t* Plo = PhiPlo + HH * HH;

    int blk = blockIdx.x;
    int b  = blk >> 4;
    int tt = (blk >> 1) & 7;
    int sh = blk & 1;
    if (b >= BB / 2) tt = 7 - tt;      // complementary tier pairing
    int t0 = tt * 16;
    int tid = threadIdx.x;
    int wv  = tid >> 6;
    int lane = tid & 63;
    int nl = lane & 15;
    int quad = lane >> 4;

    if (tid < 16) tmap16[tid] = tmapG[b * 256 + sh * 128 + t0 + tid];

    {
        const uint4* srcH = (const uint4*)BhiG;
        const uint4* srcL = (const uint4*)BloG;
        uint4* dstH = (uint4*)Phi;
        uint4* dstL = (uint4*)Plo;
        for (int i = tid; i < HH * HH / 8; i += 256) {
            dstH[i] = srcH[i];
            dstL[i] = srcL[i];
        }
    }

    float w17v[4][8];
#pragma unroll
    for (int st = 0; st < 4; st++) {
        const float* p = W1 + 17 * HH + quad * 8 + 32 * st;
        float4 a = *(const float4*)p;
        float4 bq = *(const float4*)(p + 4);
        w17v[st][0] = a.x;  w17v[st][1] = a.y;  w17v[st][2] = a.z;  w17v[st][3] = a.w;
        w17v[st][4] = bq.x; w17v[st][5] = bq.y; w17v[st][6] = bq.z; w17v[st][7] = bq.w;
    }

    __syncthreads();

    int myt = tmap16[nl];               // this lane's column t
    int key = ((b << 7) + myt) * 2 + sh;
    int cnt = cnts[key];
    int q = (cnt + 3) >> 2;              // per-wave chunk
    int mq = q;
#pragma unroll
    for (int m = 1; m < 16; m <<= 1) mq = max(mq, __shfl_xor(mq, m));
    const uchar_t* lst_s = sl_s + key * 64;
    const float*   lst_a = sl_av + key * 64;
    int i0 = wv * q;

    fx4 acc1[8];                 // sum_s mask*r2*h2   (per n, per col)
#pragma unroll
    for (int tile = 0; tile < 8; tile++) acc1[tile] = (fx4){0.f, 0.f, 0.f, 0.f};
    float c0 = 0.f;              // sum_s mask
    float c1 = 0.f;              // sum_s mask*r2*mean2

    for (int i = 0; i < mq; i++) {
        int idx = i0 + i;
        bool val = (i < q) && (idx < cnt);
        int ridx = (idx < cnt) ? idx : (cnt > 0 ? cnt - 1 : 0);
        int s = lst_s[ridx];
        float avv = val ? lst_a[ridx] : 0.f;
        const float* brow = base + (b * NN + s) * HH;

        // one pass: vv = relu(base + avv*w17); stats + pair-packed hi/lo
        short8 Hhi[4], Hlo[4];
        float sm = 0.f, s2 = 0.f;
#pragma unroll
        for (int st = 0; st < 4; st++) {
            const float* p = brow + quad * 8 + 32 * st;
            float4 b0 = *(const float4*)p;
            float4 b1q = *(const float4*)(p + 4);
            float h[8] = {b0.x, b0.y, b0.z, b0.w, b1q.x, b1q.y, b1q.z, b1q.w};
            uint_t hw[4], lw[4];
#pragma unroll
            for (int pr = 0; pr < 4; pr++) {
                float a = fmaxf(fmaf(avv, w17v[st][2 * pr], h[2 * pr]), 0.f);
                float c = fmaxf(fmaf(avv, w17v[st][2 * pr + 1], h[2 * pr + 1]), 0.f);
                sm += a; sm += c;
                s2 = fmaf(a, a, s2);
                s2 = fmaf(c, c, s2);
                pair_split(a, c, hw[pr], lw[pr]);
            }
            Hhi[st] = pack4(hw[0], hw[1], hw[2], hw[3]);
            Hlo[st] = pack4(lw[0], lw[1], lw[2], lw[3]);
        }
        sm += __shfl_xor(sm, 16); sm += __shfl_xor(sm, 32);
        s2 += __shfl_xor(s2, 16); s2 += __shfl_xor(s2, 32);
        float m1 = sm * (1.f / 128.f);
        float r1 = rsqrtf(s2 * (1.f / 128.f) - m1 * m1 + 1e-5f);
        float nm = -m1 * r1;

        // Graw = Wh'^T @ vv
        fx4 G[8];
#pragma unroll
        for (int tile = 0; tile < 8; tile++) G[tile] = (fx4){0.f, 0.f, 0.f, 0.f};
#pragma unroll
        for (int st = 0; st < 4; st++) {
            int koff = quad * 8 + 32 * st;
#pragma unroll
            for (int tile = 0; tile < 8; tile++) {
                int off = (tile * 16 + nl) * HH + (koff ^ (nl * 8));
                short8 ph = *(const short8*)(&Phi[off]);
                short8 pl = *(const short8*)(&Plo[off]);
                G[tile] = __builtin_amdgcn_mfma_f32_16x16x32_bf16(ph, Hhi[st], G[tile], 0, 0, 0);
                G[tile] = __builtin_amdgcn_mfma_f32_16x16x32_bf16(pl, Hhi[st], G[tile], 0, 0, 0);
                G[tile] = __builtin_amdgcn_mfma_f32_16x16x32_bf16(ph, Hlo[st], G[tile], 0, 0, 0);
            }
        }

        // LN1 correction + relu; LN2 stats (in-lane over 32 n + 2 shuffles)
        float sm2 = 0.f, ss2 = 0.f;
#pragma unroll
        for (int tile = 0; tile < 8; tile++) {
            float4 w4 = *(const float4*)(W1sg + tile * 16 + quad * 4);
            float4 c4 = *(const float4*)(cbv + tile * 16 + quad * 4);
            float wa[4] = {w4.x, w4.y, w4.z, w4.w};
            float ca[4] = {c4.x, c4.y, c4.z, c4.w};
#pragma unroll
            for (int r = 0; r < 4; r++) {
                float pre = fmaf(r1, G[tile][r], fmaf(nm, wa[r], ca[r]));
                float h2 = fmaxf(pre, 0.f);
                G[tile][r] = h2;
                sm2 += h2;
                ss2 = fmaf(h2, h2, ss2);
            }
        }
        sm2 += __shfl_xor(sm2, 16); sm2 += __shfl_xor(sm2, 32);
        ss2 += __shfl_xor(ss2, 16); ss2 += __shfl_xor(ss2, 32);
        float mean2 = sm2 * (1.f / 128.f);
        float r2 = rsqrtf(ss2 * (1.f / 128.f) - mean2 * mean2 + 1e-5f);
        float msk = val ? 1.f : 0.f;
        float mr2 = msk * r2;

#pragma unroll
        for (int tile = 0; tile < 8; tile++)
#pragma unroll
            for (int r = 0; r < 4; r++)
                acc1[tile][r] = fmaf(mr2, G[tile][r], acc1[tile][r]);
        c0 += msk;
        c1 = fmaf(mr2, mean2, c1);
    }

    // ---- epilogue: xv = gh*(acc1 - c1) + beh*c0 ;  cross-wave LDS reduce,
    //      then coalesced atomics to PERMUTED rows (row = tmap16[t]) ----
    __syncthreads();                       // Phi/Plo dead; reuse as f32 slab
    float* slab = (float*)PhiPlo;          // [4 waves][16 cols][stride 132]
#pragma unroll
    for (int tile = 0; tile < 8; tile++) {
        float4 g4 = *(const float4*)(ghp + tile * 16 + quad * 4);
        float4 be4 = *(const float4*)(behp + tile * 16 + quad * 4);
        float gv[4] = {g4.x, g4.y, g4.z, g4.w};
        float bv[4] = {be4.x, be4.y, be4.z, be4.w};
#pragma unroll
        for (int r = 0; r < 4; r++) {
            float xv = fmaf(gv[r], acc1[tile][r] - c1, bv[r] * c0);
            slab[(wv * 16 + nl) * 132 + tile * 16 + quad * 4 + r] = xv;
        }
    }
    __syncthreads();
    for (int e = tid; e < 16 * HH; e += 256) {
        int t = e >> 7, n = e & 127;
        float vsum = slab[t * 132 + n] + slab[(16 + t) * 132 + n]
                   + slab[(32 + t) * 132 + n] + slab[(48 + t) * 132 + n];
        atomicAdd(&x0[(b * NN + tmap16[t]) * HH + n], vsum);
    }
}

// ---------------- K5: qkvs via MFMA, 512 blocks, LDS-staged weights --------
// All 4 waves of a block read IDENTICAL weight-plane addresses per MFMA;
// round-14: stage each mat's 32-col slice (both planes) into LDS once
// (cooperative uint4 copy) and feed MFMAs from LDS -- same bytes, same
// swizzle, same MFMA order -> bit-identical.  Layer-2 agent skip: stage
// decision is block-uniform (havea_blk); per-wave compute skip unchanged;
// barriers uniform.
template <int IN>
__global__ void __launch_bounds__(256) k_qkvs_mfma(
    const float* x, const ushort_t* Whi, const ushort_t* Wlo,
    const float* b0, const float* b1, const float* b2, const float* b3,
    float* q, float* skipo,
    ushort_t* khi, ushort_t* klo, ushort_t* vThi, ushort_t* vTlo,
    const int* agentp)
{
    const int ST = IN / 32;
    __shared__ __align__(16) ushort_t BhL[32 * IN];   // 8/16 KB
    __shared__ __align__(16) ushort_t BlL[32 * IN];

    int blk = blockIdx.x;             // 512 = 64 m-blocks * 8 col slices
    int m0 = (blk >> 3) * 64;
    int nsl = blk & 7;                // 32-col slice
    int tid = threadIdx.x;
    int wv = tid >> 6;
    int lane = tid & 63;
    int nl = lane & 15;
    int quad = lane >> 4;
    int row = m0 + wv * 16 + nl;

    short8 Ahi[ST], Alo[ST];
    const float* xrow = x + (long)row * IN;
#pragma unroll
    for (int st = 0; st < ST; st++) {
        const float* p = xrow + quad * 8 + 32 * st;
        float4 a4 = *(const float4*)p;
        float4 b4 = *(const float4*)(p + 4);
        float h[8] = {a4.x, a4.y, a4.z, a4.w, b4.x, b4.y, b4.z, b4.w};
        uint_t hw[4], lw[4];
#pragma unroll
        for (int pr = 0; pr < 4; pr++)
            pair_split(h[2 * pr], h[2 * pr + 1], hw[pr], lw[pr]);
        Ahi[st] = pack4(hw[0], hw[1], hw[2], hw[3]);
        Alo[st] = pack4(lw[0], lw[1], lw[2], lw[3]);
    }

    const float* bs_[4] = {b0, b1, b2, b3};
    int rw0 = m0 + wv * 16;                  // wave's 16-row tile start
    bool agset = (agentp != nullptr);
    int agrow = agset ? agentp[m0 >> 7] : -1;
    // wave-level: agent row in this wave's 16-row tile
    bool havea = agset && ((agrow >> 4) == ((rw0 & 127) >> 4));
    // block-level: agent row in this block's 64 rows (uniform)
    bool havea_blk = agset && ((agrow >> 6) == ((m0 & 127) >> 6));

#pragma unroll
    for (int mat = 0; mat < 4; mat++) {
        bool doMat = !((mat == 0 || mat == 3) && agset && !havea_blk);
        if (doMat) {
            const uint4* srcH = (const uint4*)(Whi + (mat * 256 + nsl * 32) * IN);
            const uint4* srcL = (const uint4*)(Wlo + (mat * 256 + nsl * 32) * IN);
            uint4* dH = (uint4*)BhL;
            uint4* dL = (uint4*)BlL;
#pragma unroll
            for (int i = tid; i < 32 * IN / 8; i += 256) {
                dH[i] = srcH[i];
                dL[i] = srcL[i];
            }
        }
        __syncthreads();

        bool doWave = doMat && !((mat == 0 || mat == 3) && agset && !havea);
        if (doWave) {
            fx4 G[2];
#pragma unroll
            for (int tile = 0; tile < 2; tile++) {
                float bc = bs_[mat][nsl * 32 + tile * 16 + nl];
                G[tile] = (fx4){bc, bc, bc, bc};
            }
#pragma unroll
            for (int st = 0; st < ST; st++) {
                int koff = quad * 8 + 32 * st;
#pragma unroll
                for (int tile = 0; tile < 2; tile++) {
                    int off = (tile * 16 + nl) * IN + (koff ^ (nl * 8));
                    short8 bh8 = *(const short8*)(&BhL[off]);
                    short8 bl8 = *(const short8*)(&BlL[off]);
                    G[tile] = __builtin_amdgcn_mfma_f32_16x16x32_bf16(Ahi[st], bh8, G[tile], 0, 0, 0);
                    G[tile] = __builtin_amdgcn_mfma_f32_16x16x32_bf16(Alo[st], bh8, G[tile], 0, 0, 0);
                    G[tile] = __builtin_amdgcn_mfma_f32_16x16x32_bf16(Ahi[st], bl8, G[tile], 0, 0, 0);
                }
            }
            int row0 = m0 + wv * 16 + quad * 4;          // rows r=0..3
            if (mat == 0 || mat == 3) {
                float* om = (mat == 0) ? q : skipo;
#pragma unroll
                for (int tile = 0; tile < 2; tile++)
#pragma unroll
                    for (int r = 0; r < 4; r++)
                        om[(row0 + r) * HD + nsl * 32 + tile * 16 + nl] = G[tile][r];
            } else if (mat == 1) {
                // K planes, layout [row=b*128+s][256]
#pragma unroll
                for (int tile = 0; tile < 2; tile++) {
                    int col = nsl * 32 + tile * 16 + nl;
#pragma unroll
                    for (int r = 0; r < 4; r++) {
                        float gv = G[tile][r];
                        ushort_t hb = f2us_tr(gv);
                        khi[(row0 + r) * HD + col] = hb;
                        klo[(row0 + r) * HD + col] = f2us_tr(gv - us2f(hb));
                    }
                }
            } else {
                // vT planes: vT[dg = b*256 + col][128 s], 4 consecutive s
                int bb = row0 >> 7;
                int s0 = row0 & 127;
#pragma unroll
                for (int tile = 0; tile < 2; tile++) {
                    int col = nsl * 32 + tile * 16 + nl;
                    int dg = bb * 256 + col;
                    ushort4 h4, l4;
                    float g0 = G[tile][0], g1 = G[tile][1], g2 = G[tile][2], g3 = G[tile][3];
                    ushort_t h0 = f2us_tr(g0), h1 = f2us_tr(g1), h2 = f2us_tr(g2), h3 = f2us_tr(g3);
                    h4.x = h0; h4.y = h1; h4.z = h2; h4.w = h3;
                    l4.x = f2us_tr(g0 - us2f(h0));
                    l4.y = f2us_tr(g1 - us2f(h1));
                    l4.z = f2us_tr(g2 - us2f(h2));
                    l4.w = f2us_tr(g3 - us2f(h3));
                    *(ushort4*)&vThi[dg * NN + s0] = h4;
                    *(ushort4*)&vTlo[dg * NN + s0] = l4;
                }
            }
        }
        __syncthreads();
    }
}

// ---------------- K6: attention via MFMA, 4 waves per (b,h,16-t tile) ------
// (unchanged from round 13)
__global__ void __launch_bounds__(256) k_attn_mfma(
    const float* qb, const ushort_t* khi, const ushort_t* klo,
    const ushort_t* vThi, const ushort_t* vTlo,
    const float* adjvT, const float* We, const float* skip, float* xout,
    const int* agentp, float* outp)
{
    __shared__ float aL[16][132];     // alpha C->A round-trip (8.4 KB)
    __shared__ float qeL[16];
    __shared__ float mxL[4][16];
    __shared__ float dnL[4][16];
    __shared__ float ebL[4][16];

    int blk = blockIdx.x;
    int b, h, tt;
    if (agentp == nullptr) {          // 1024 = 32b*4h*8tt
        b = blk >> 5; h = (blk >> 3) & 3; tt = blk & 7;
    } else {                          // 128 = 32b*4h
        b = blk >> 2; h = blk & 3; tt = agentp[b] >> 4;
    }
    int t0 = tt * 16;
    int tid = threadIdx.x;
    int w   = tid >> 6;               // wave 0..3
    int lane = tid & 63;
    int nl = lane & 15;
    int quad = lane >> 4;

    // ---- Q A-frags (split hi/lo) + qe partial (q . we) ----
    short8 Qhi[2], Qlo[2];
    float qe = 0.f;
#pragma unroll
    for (int ks = 0; ks < 2; ks++) {
        const float* p = qb + (b * NN + t0 + nl) * HD + h * DHEAD + quad * 8 + 32 * ks;
        const float* wp = We + h * DHEAD + quad * 8 + 32 * ks;
        float4 a0 = *(const float4*)p;
        float4 a1 = *(const float4*)(p + 4);
        float4 w0 = *(const float4*)wp;
        float4 w1 = *(const float4*)(wp + 4);
        float hv[8] = {a0.x, a0.y, a0.z, a0.w, a1.x, a1.y, a1.z, a1.w};
        float wv8[8] = {w0.x, w0.y, w0.z, w0.w, w1.x, w1.y, w1.z, w1.w};
        uint_t hw[4], lw[4];
#pragma unroll
        for (int pr = 0; pr < 4; pr++) {
            float a = hv[2 * pr], c = hv[2 * pr + 1];
            qe = fmaf(a, wv8[2 * pr], qe);
            qe = fmaf(c, wv8[2 * pr + 1], qe);
            pair_split(a, c, hw[pr], lw[pr]);
        }
        Qhi[ks] = pack4(hw[0], hw[1], hw[2], hw[3]);
        Qlo[ks] = pack4(lw[0], lw[1], lw[2], lw[3]);
    }
    qe += __shfl_xor(qe, 16);
    qe += __shfl_xor(qe, 32);
    if (w == 0 && lane < 16) qeL[lane] = qe;   // qe for t = lane
    __syncthreads();
    float qe_r[4];
#pragma unroll
    for (int r = 0; r < 4; r++) qe_r[r] = qeL[quad * 4 + r];
    float we_dv = We[h * DHEAD + w * 16 + nl];

    // ---- QK^T: wave's 2 s-tiles (global st = w*2 + st') ----
    fx4 S[2];
#pragma unroll
    for (int st = 0; st < 2; st++) S[st] = (fx4){0.f, 0.f, 0.f, 0.f};
#pragma unroll
    for (int ks = 0; ks < 2; ks++) {
#pragma unroll
        for (int st = 0; st < 2; st++) {
            long off = (long)(b * NN + (w * 2 + st) * 16 + nl) * HD + h * DHEAD + quad * 8 + 32 * ks;
            short8 bh8 = *(const short8*)(khi + off);
            short8 bl8 = *(const short8*)(klo + off);
            S[st] = __builtin_amdgcn_mfma_f32_16x16x32_bf16(Qhi[ks], bh8, S[st], 0, 0, 0);
            S[st] = __builtin_amdgcn_mfma_f32_16x16x32_bf16(Qlo[ks], bh8, S[st], 0, 0, 0);
            S[st] = __builtin_amdgcn_mfma_f32_16x16x32_bf16(Qhi[ks], bl8, S[st], 0, 0, 0);
        }
    }

    // ---- masked logits (D-layout: row t = quad*4+r, col s = (w*2+st)*16+nl)
    float av[2][4];
#pragma unroll
    for (int st = 0; st < 2; st++)
#pragma unroll
        for (int r = 0; r < 4; r++)
            av[st][r] = adjvT[(b * NN + t0 + quad * 4 + r) * NN + (w * 2 + st) * 16 + nl];
#pragma unroll
    for (int st = 0; st < 2; st++)
#pragma unroll
        for (int r = 0; r < 4; r++) {
            float a = av[st][r];
            S[st][r] = (a != 0.f) ? (S[st][r] + a * qe_r[r]) * 0.125f : -1e30f;
        }

    // ---- partial row max, combine across 4 waves ----
    float mxp[4];
#pragma unroll
    for (int r = 0; r < 4; r++) {
        float m = fmaxf(S[0][r], S[1][r]);
#pragma unroll
        for (int mm = 1; mm < 16; mm <<= 1) m = fmaxf(m, __shfl_xor(m, mm));
        mxp[r] = m;
    }
    if (nl == 0) {
#pragma unroll
        for (int r = 0; r < 4; r++) mxL[w][quad * 4 + r] = mxp[r];
    }
    __syncthreads();
    float mx[4];
#pragma unroll
    for (int r = 0; r < 4; r++) {
        int row = quad * 4 + r;
        mx[r] = fmaxf(fmaxf(mxL[0][row], mxL[1][row]),
                      fmaxf(mxL[2][row], mxL[3][row]));
    }

    // ---- e = exp(S - mx); partial den & e.av, combine ----
    float dnp[4] = {0.f, 0.f, 0.f, 0.f}, ebp[4] = {0.f, 0.f, 0.f, 0.f};
#pragma unroll
    for (int st = 0; st < 2; st++)
#pragma unroll
        for (int r = 0; r < 4; r++) {
            float e = (av[st][r] != 0.f) ? __expf(S[st][r] - mx[r]) : 0.f;
            S[st][r] = e;
            dnp[r] += e;
            ebp[r] = fmaf(e, av[st][r], ebp[r]);
        }
#pragma unroll
    for (int r = 0; r < 4; r++) {
#pragma unroll
        for (int mm = 1; mm < 16; mm <<= 1) {
            dnp[r] += __shfl_xor(dnp[r], mm);
            ebp[r] += __shfl_xor(ebp[r], mm);
        }
    }
    if (nl == 0) {
#pragma unroll
        for (int r = 0; r < 4; r++) {
            dnL[w][quad * 4 + r] = dnp[r];
            ebL[w][quad * 4 + r] = ebp[r];
        }
    }
    __syncthreads();
    float rden[4], beta[4];
#pragma unroll
    for (int r = 0; r < 4; r++) {
        int row = quad * 4 + r;
        float d = ((dnL[0][row] + dnL[1][row]) + dnL[2][row]) + dnL[3][row];
        rden[r] = 1.f / fmaxf(d, 1e-16f);
        beta[r] = (((ebL[0][row] + ebL[1][row]) + ebL[2][row]) + ebL[3][row]) * rden[r];
    }

    // ---- alpha -> aL (wave writes its 32-column slice) ----
#pragma unroll
    for (int st = 0; st < 2; st++)
#pragma unroll
        for (int r = 0; r < 4; r++)
            aL[quad * 4 + r][(w * 2 + st) * 16 + nl] = S[st][r] * rden[r];
    __syncthreads();

    // ---- A-frags over full s range ----
    short8 Ah[4];
#pragma unroll
    for (int ks = 0; ks < 4; ks++) {
        const float* p = &aL[nl][quad * 8 + 32 * ks];
        float4 a0 = *(const float4*)p;
        float4 a1 = *(const float4*)(p + 4);
        float hv[8] = {a0.x, a0.y, a0.z, a0.w, a1.x, a1.y, a1.z, a1.w};
        uint_t ww[4];
#pragma unroll
        for (int pr = 0; pr < 4; pr++) ww[pr] = pair_hi(hv[2 * pr], hv[2 * pr + 1]);
        Ah[ks] = pack4(ww[0], ww[1], ww[2], ww[3]);
    }

    // ---- PV: wave's output-d quarter (nt = w) ----
    fx4 G;
#pragma unroll
    for (int r = 0; r < 4; r++) G[r] = beta[r] * we_dv;
    {
        long dg = (long)(b * 256 + h * DHEAD + w * 16 + nl);
        const ushort_t* vhB = vThi + dg * NN;
        const ushort_t* vlB = vTlo + dg * NN;
#pragma unroll
        for (int ks = 0; ks < 4; ks++) {
            const short8 vh = *(const short8*)(vhB + quad * 8 + 32 * ks);
            const short8 vl = *(const short8*)(vlB + quad * 8 + 32 * ks);
            G = __builtin_amdgcn_mfma_f32_16x16x32_bf16(Ah[ks], vh, G, 0, 0, 0);
            G = __builtin_amdgcn_mfma_f32_16x16x32_bf16(Ah[ks], vl, G, 0, 0, 0);
        }
    }

    // ---- epilogue ----
    if (agentp == nullptr) {
        // layer 1: full relu(out + skip) -> xout
#pragma unroll
        for (int r = 0; r < 4; r++) {
            int gi = (b * NN + t0 + quad * 4 + r) * HD + h * DHEAD + w * 16 + nl;
            xout[gi] = fmaxf(G[r] + skip[gi], 0.f);
        }
    } else {
        // layer 2 + fused gather: only the agent row reaches the output
        int ag = agentp[b];
#pragma unroll
        for (int r = 0; r < 4; r++) {
            int t = t0 + quad * 4 + r;
            if (t == ag) {
                int d = h * DHEAD + w * 16 + nl;
                int gi = (b * NN + t) * HD + d;
                outp[b * HD + d] = fmaxf(G[r] + skip[gi], 0.f);
            }
        }
    }
}

// ---------------- launch ----------------
extern "C" void kernel_launch(void* const* d_in, const int* in_sizes, int n_in,
                              void* d_out, int out_size, void* d_ws, size_t ws_size,
                              hipStream_t stream) {
    float* out = (float*)d_out;
    (void)hipGetLastError();

    bool ok = (n_in == 31) && in_sizes[0] == BB * NN * FF && in_sizes[2] == BB * NN * NN
              && in_sizes[5] == (FF + EE + 1) * HH && in_sizes[13] == HH * HD
              && in_sizes[22] == HD * HD && out_size == BB * HD;
    if (!ok) { k_sent<<<32, 256, 0, stream>>>(out, -30000.f); return; }

    const size_t WS_NEED = (size_t)8912896 * 4;
    if (ws_size < WS_NEED) { k_sent<<<32, 256, 0, stream>>>(out, -20000.f); return; }

    const float* nf    = (const float*)d_in[0];
    const int*   et    = (const int*)d_in[1];
    const float* adj   = (const float*)d_in[2];
    const int*   agent = (const int*)d_in[3];
    const float* emb   = (const float*)d_in[4];
    const float* W1    = (const float*)d_in[5];
    const float* b1    = (const float*)d_in[6];
    const float* g1    = (const float*)d_in[7];
    const float* be1   = (const float*)d_in[8];
    const float* Wh    = (const float*)d_in[9];
    const float* bh    = (const float*)d_in[10];
    const float* gh    = (const float*)d_in[11];
    const float* beh   = (const float*)d_in[12];
    const float* Wq1   = (const float*)d_in[13];
    const float* bq1   = (const float*)d_in[14];
    const float* Wk1   = (const float*)d_in[15];
    const float* bk1   = (const float*)d_in[16];
    const float* Wv1   = (const float*)d_in[17];
    const float* bv1   = (const float*)d_in[18];
    const float* We1   = (const float*)d_in[19];
    const float* Ws1   = (const float*)d_in[20];
    const float* bs1   = (const float*)d_in[21];
    const float* Wq2   = (const float*)d_in[22];
    const float* bq2   = (const float*)d_in[23];
    const float* Wk2   = (const float*)d_in[24];
    const float* bk2   = (const float*)d_in[25];
    const float* Wv2   = (const float*)d_in[26];
    const float* bv2   = (const float*)d_in[27];
    const float* We2   = (const float*)d_in[28];
    const float* Ws2   = (const float*)d_in[29];
    const float* bs2   = (const float*)d_in[30];

    float* ws   = (float*)d_ws;
    float* slav = ws;                              // 524288 f region (sl_av)
    float* base = ws + 524288;                     // 524288 f
    float* x0   = base + BB * NN * HH;             // 524288 f
    float* q    = x0 + BB * NN * HH;               // 1048576 f
    float* kreg = q + BB * NN * HD;                // 1048576 f -> khi/klo
    float* vreg = kreg + BB * NN * HD;             // 1048576 f -> vThi/vTlo
    float* skip = vreg + BB * NN * HD;             // 1048576 f
    float* areg = skip + BB * NN * HD;             // 1048576 f -> planes + adjvT + sl_s
    float* x1   = areg + BB * NN * HD;
    float* x2   = x1 + BB * NN * HD;

    // econv prep planes in q region (q first written AFTER econv)
    ushort_t* BhiG = (ushort_t*)q;
    ushort_t* BloG = BhiG + HH * HH;
    float*    W1sW = q + 16384;
    float*    cbW  = q + 16512;
    int*      cnts = (int*)(q + 17024);            // 8192 ints
    int*      tmapG = (int*)(q + 25216);           // 8192 ints (rank -> t)

    // K / vT planes
    ushort_t* khi  = (ushort_t*)kreg;              // 1048576 ush
    ushort_t* klo  = khi + BB * NN * HD;           // 1048576 ush
    ushort_t* vThi = (ushort_t*)vreg;
    ushort_t* vTlo = vThi + BB * NN * HD;

    // qkvs weight planes + adjvT + sl_s in areg (4 MB):
    // planes 1.5 MB + adjvT 2 MB + sl_s 0.5 MB = 4 MB exactly
    ushort_t* WhA = (ushort_t*)areg;               // 4*256*128 ush
    ushort_t* WlA = WhA + 4 * 256 * HH;
    ushort_t* WhB = WlA + 4 * 256 * HH;            // 4*256*256 ush
    ushort_t* WlB = WhB + 4 * 256 * HD;
    float* adjvT  = areg + 393216;                 // 524288 f, past planes
    uchar_t* sl_s = (uchar_t*)(areg + 917504);     // 524288 uchars, tail

    int fail = 0;
    hipError_t e;
#define CHK(stage) do { e = hipGetLastError(); if (e != hipSuccess && fail == 0) fail = (stage); } while (0)

    k_prep_all<<<1984, 256, 0, stream>>>(
        adj, adjvT, sl_s, slav, cnts, tmapG,
        nf, et, emb, W1, b1, base, x0,
        Wh, g1, be1, bh, BhiG, BloG, W1sW, cbW,
        Wq1, Wk1, Wv1, Ws1, WhA, WlA,
        Wq2, Wk2, Wv2, Ws2, WhB, WlB);                                               CHK(1);

    k_econv_mfma<<<512, 256, 0, stream>>>(sl_s, slav, cnts, tmapG, base, W1,
                                          BhiG, BloG, W1sW, cbW, gh, beh, x0);       CHK(2);

    k_qkvs_mfma<HH><<<512, 256, 0, stream>>>(x0, WhA, WlA, bq1, bk1, bv1, bs1,
                                             q, skip, khi, klo, vThi, vTlo,
                                             nullptr);                               CHK(3);
    k_attn_mfma<<<1024, 256, 0, stream>>>(q, khi, klo, vThi, vTlo, adjvT, We1,
                                          skip, x1, nullptr, nullptr);               CHK(4);

    k_qkvs_mfma<HD><<<512, 256, 0, stream>>>(x1, WhB, WlB, bq2, bk2, bv2, bs2,
                                             q, skip, khi, klo, vThi, vTlo,
                                             agent);                                 CHK(5);
    k_attn_mfma<<<128, 256, 0, stream>>>(q, khi, klo, vThi, vTlo, adjvT, We2,
                                         skip, x2, agent, out);                      CHK(6);
#undef CHK

    if (fail != 0)
        k_sent<<<32, 256, 0, stream>>>(out, -(1000.f + 500.f * (float)fail));
}

// Round 15
// 239.281 us; speedup vs baseline: 1.0593x; 1.0044x over previous
//
#include <hip/hip_runtime.h>
#include <hip/hip_bf16.h>

typedef __hip_bfloat16 bf16;
typedef unsigned short ushort_t;
typedef unsigned char uchar_t;
typedef unsigned int uint_t;
typedef __attribute__((ext_vector_type(8))) short short8;
typedef __attribute__((ext_vector_type(4))) float fx4;
typedef __attribute__((ext_vector_type(4))) unsigned int uintx4;

#define BB 32
#define NN 128
#define FF 9
#define EE 8
#define HH 128
#define HD 256
#define NHEAD 4
#define DHEAD 64

__device__ __forceinline__ float us2f(ushort_t u) {
    return __uint_as_float(((unsigned int)u) << 16);
}
// truncation split: hi = trunc16(v), lo = v - hi (lo exact in f32)
__device__ __forceinline__ ushort_t f2us_tr(float f) {
    return (ushort_t)(__float_as_uint(f) >> 16);
}
__device__ __forceinline__ short8 pack4(uint_t w0, uint_t w1, uint_t w2, uint_t w3) {
    uintx4 u = (uintx4){w0, w1, w2, w3};
    return __builtin_bit_cast(short8, u);
}
// pair split: a -> low short of word, c -> high short (bit-identical to
// per-element f2us_tr path: keep = bits & 0xffff0000 == us2f(f2us_tr(x)))
__device__ __forceinline__ void pair_split(float a, float c, uint_t& hw, uint_t& lw) {
    uint_t ua = __float_as_uint(a), uc = __float_as_uint(c);
    uint_t ka = ua & 0xffff0000u, kc = uc & 0xffff0000u;
    float la = a - __uint_as_float(ka);
    float lc = c - __uint_as_float(kc);
    hw = (ua >> 16) | kc;
    lw = (__float_as_uint(la) >> 16) | (__float_as_uint(lc) & 0xffff0000u);
}
__device__ __forceinline__ uint_t pair_hi(float a, float c) {
    return (__float_as_uint(a) >> 16) | (__float_as_uint(c) & 0xffff0000u);
}

__global__ void TransformerConvNet_85315230367963_kernel() {}

__global__ void k_sent(float* out, float val) {
    out[blockIdx.x * 256 + threadIdx.x] = val;
}

// ---------------- K_prep_all: prep work needed BEFORE econv, ONE launch ----
// blocks [0,128):      adjvT + lists + cnts, one (b,chunk) per block
// blocks [128,160):    rank per b (independent cnt recompute -> tmapG)
// blocks [160,1184):   base = src @ W1[:17] + b1          (1024 blocks)
// blocks [1184,1440):  zero x0                            (256 blocks)
// blocks [1440,1472):  Wh' split hi/lo + W1s/cb           (32 blocks)
// (prepw layer1/2 moved into the econv launch: no consumer until qkvs,
//  so they fill econv's block-drain shadow instead of stretching prep)
__global__ void __launch_bounds__(256) k_prep_all(
    const float* adj, float* adjvT, uchar_t* sl_s, float* sl_av, int* cnts,
    int* tmapG,
    const float* nf, const int* et, const float* emb, const float* W1,
    const float* b1, float* base, float* x0,
    const float* Wh, const float* g1, const float* be1, const float* bh,
    ushort_t* BhiG, ushort_t* BloG, float* W1s, float* cbv)
{
    __shared__ float tileF[128 * 33];     // 16.9 KB (section 1a)
    __shared__ int   cntP[512];           // (section 1b) [p][t][sh]
    __shared__ int   combL[256];          // (section 1b) [t][sh]

    int blk = blockIdx.x;
    int tid = threadIdx.x;

    if (blk < 128) {
        // ---- adjvT + ballot-compacted lists + cnts, one (b, 32-t chunk) ----
        int b = blk >> 2, c = blk & 3;
        int wv = tid >> 6, lane = tid & 63;
        int t0c = c * 32;
#pragma unroll
        for (int pass = 0; pass < 16; pass++) {
            int s = pass * 8 + (tid >> 5);
            int tq = tid & 31;
            float a = adj[(b * NN + s) * NN + t0c + tq];
            float av = (a > 0.f && a < 1.0f) ? a : 0.f;
            tileF[s * 33 + tq] = av;
        }
        __syncthreads();
#pragma unroll
        for (int j = 0; j < 16; j++) {
            int u = wv * 16 + j;               // 64 (t,sh) units
            int tq = u >> 1, sh = u & 1;
            int t = t0c + tq;
            int s = sh * 64 + lane;
            float av = tileF[s * 33 + tq];
            adjvT[(b * NN + t) * NN + s] = av;
            unsigned long long mask = __ballot(av != 0.f);
            int key = (b * NN + t) * 2 + sh;
            if (av != 0.f) {
                int pos = __popcll(mask & ((1ull << lane) - 1ull));
                sl_s[key * 64 + pos] = (uchar_t)s;
                sl_av[key * 64 + pos] = av;
            }
            if (lane == 0) {
                cnts[key] = (int)__popcll(mask);
                if (mask == 0ull) { sl_s[key * 64] = 0; sl_av[key * 64] = 0.f; }
            }
        }
    } else if (blk < 160) {
        // ---- rank per b: independent cnt recompute (coalesced) + rank ----
        int b = blk - 128;
        int t = tid & 127, p = tid >> 7;
        int c0 = 0, c1 = 0;
        for (int k = 0; k < 32; k++) {
            float a = adj[(b * NN + (2 * k + p)) * NN + t];
            c0 += (a > 0.f && a < 1.0f) ? 1 : 0;
        }
        for (int k = 32; k < 64; k++) {
            float a = adj[(b * NN + (2 * k + p)) * NN + t];
            c1 += (a > 0.f && a < 1.0f) ? 1 : 0;
        }
        cntP[p * 256 + t * 2 + 0] = c0;
        cntP[p * 256 + t * 2 + 1] = c1;
        __syncthreads();
        int sh = tid >> 7, i = tid & 127;
        int ci = cntP[0 * 256 + i * 2 + sh] + cntP[1 * 256 + i * 2 + sh];
        combL[i * 2 + sh] = ci;
        __syncthreads();
        int rank = 0;
        for (int j = 0; j < 128; j++) {
            int cj = combL[j * 2 + sh];
            rank += (cj > ci) || (cj == ci && j < i);
        }
        tmapG[b * 256 + sh * 128 + rank] = i;
    } else if (blk < 1184) {
        // ---- base rows (4 per block)
        int bblk = blk - 160;
        int c = tid & 127;
#pragma unroll
        for (int rr = 0; rr < 2; rr++) {
            int bs = bblk * 4 + rr * 2 + (tid >> 7);
            int ty = et[bs];
            float acc = b1[c];
            for (int f = 0; f < FF; f++)
                acc += nf[bs * FF + f] * W1[f * HH + c];
            for (int e2 = 0; e2 < EE; e2++)
                acc += emb[ty * EE + e2] * W1[(FF + e2) * HH + c];
            base[bs * HH + c] = acc;
        }
    } else if (blk < 1440) {
        // ---- zero x0 (524288 floats = 131072 float4)
        int zblk = blk - 1184;
        float4* p = (float4*)x0 + zblk * 512 + tid * 2;
        p[0] = (float4){0.f, 0.f, 0.f, 0.f};
        p[1] = (float4){0.f, 0.f, 0.f, 0.f};
    } else {
        // ---- Wh' = g1*Wh split bf16 hi/lo, swizzled; W1s/cb (wave per n)
        int n = (blk - 1440) * 4 + (tid >> 6);
        int t = tid & 63;
        int sw = 8 * (n & 15);
        float s1 = 0.f, s2 = 0.f;
#pragma unroll
        for (int kk = 0; kk < 2; kk++) {
            int k = t + kk * 64;
            float w = Wh[k * HH + n];
            float wp = g1[k] * w;
            ushort_t hb = f2us_tr(wp);
            float lo = wp - us2f(hb);
            BhiG[n * HH + (k ^ sw)] = hb;
            BloG[n * HH + (k ^ sw)] = f2us_tr(lo);
            s1 += wp;
            s2 += be1[k] * w;
        }
        for (int m = 1; m < 64; m <<= 1) {
            s1 += __shfl_xor(s1, m);
            s2 += __shfl_xor(s2, m);
        }
        if (t == 0) { W1s[n] = s1; cbv[n] = s2 + bh[n]; }
    }
}

// ---------------- K3: embed conv (blocks 0-511) + prepw (blocks 512-1023) --
// econv unchanged (72-73 us canary).  prepw sections relocated here: their
// outputs (WhA/WlA/WhB/WlB) are first consumed by qkvs, so they fill the
// econv block-drain shadow instead of stretching the prep critical path.
__global__ void __launch_bounds__(256) k_econv_mfma(
    const uchar_t* sl_s, const float* sl_av, const int* cnts, const int* tmapG,
    const float* base, const float* W1,
    const ushort_t* BhiG, const ushort_t* BloG,
    const float* W1sg, const float* cbv,
    const float* ghp, const float* behp, float* x0,
    const float* Wq1, const float* Wk1, const float* Wv1, const float* Ws1,
    ushort_t* WhA, ushort_t* WlA,
    const float* Wq2, const float* Wk2, const float* Wv2, const float* Ws2,
    ushort_t* WhB, ushort_t* WlB)
{
    __shared__ __align__(16) ushort_t PhiPlo[2 * HH * HH];   // 64 KB
    __shared__ int tmap16[16];                               // rank -> t (tile)
    ushort_t* Phi = PhiPlo;
    ushort_t* Plo = PhiPlo + HH * HH;

    int blk = blockIdx.x;
    int tid = threadIdx.x;

    if (blk >= 512) {
        // ---- prepw tail-filler blocks ----
        int pblk = blk - 512;
        if (pblk < 256) {
            // prepw layer 1 (IN = HH), key = (mat,n), wave per key
            int key = pblk * 4 + (tid >> 6);
            int lane = tid & 63;
            int mat = key >> 8, n = key & 255;
            const float* W = (mat == 0) ? Wq1 : (mat == 1) ? Wk1 : (mat == 2) ? Wv1 : Ws1;
            ushort_t* hi = WhA + mat * 256 * HH;
            ushort_t* lo = WlA + mat * 256 * HH;
            int sw = 8 * (n & 15);
            for (int k = lane; k < HH; k += 64) {
                float w = W[k * HD + n];
                ushort_t hb = f2us_tr(w);
                float l = w - us2f(hb);
                hi[n * HH + (k ^ sw)] = hb;
                lo[n * HH + (k ^ sw)] = f2us_tr(l);
            }
        } else {
            // prepw layer 2 (IN = HD)
            int key = (pblk - 256) * 4 + (tid >> 6);
            int lane = tid & 63;
            int mat = key >> 8, n = key & 255;
            const float* W = (mat == 0) ? Wq2 : (mat == 1) ? Wk2 : (mat == 2) ? Wv2 : Ws2;
            ushort_t* hi = WhB + mat * 256 * HD;
            ushort_t* lo = WlB + mat * 256 * HD;
            int sw = 8 * (n & 15);
            for (int k = lane; k < HD; k += 64) {
                float w = W[k * HD + n];
                ushort_t hb = f2us_tr(w);
                float l = w - us2f(hb);
                hi[n * HD + (k ^ sw)] = hb;
                lo[n * HD + (k ^ sw)] = f2us_tr(l);
            }
        }
        return;
    }

    int b  = blk >> 4;
    int tt = (blk >> 1) & 7;
    int sh = blk & 1;
    if (b >= BB / 2) tt = 7 - tt;      // complementary tier pairing
    int t0 = tt * 16;
    int wv  = tid >> 6;
    int lane = tid & 63;
    int nl = lane & 15;
    int quad = lane >> 4;

    if (tid < 16) tmap16[tid] = tmapG[b * 256 + sh * 128 + t0 + tid];

    {
        const uint4* srcH = (const uint4*)BhiG;
        const uint4* srcL = (const uint4*)BloG;
        uint4* dstH = (uint4*)Phi;
        uint4* dstL = (uint4*)Plo;
        for (int i = tid; i < HH * HH / 8; i += 256) {
            dstH[i] = srcH[i];
            dstL[i] = srcL[i];
        }
    }

    float w17v[4][8];
#pragma unroll
    for (int st = 0; st < 4; st++) {
        const float* p = W1 + 17 * HH + quad * 8 + 32 * st;
        float4 a = *(const float4*)p;
        float4 bq = *(const float4*)(p + 4);
        w17v[st][0] = a.x;  w17v[st][1] = a.y;  w17v[st][2] = a.z;  w17v[st][3] = a.w;
        w17v[st][4] = bq.x; w17v[st][5] = bq.y; w17v[st][6] = bq.z; w17v[st][7] = bq.w;
    }

    __syncthreads();

    int myt = tmap16[nl];               // this lane's column t
    int key = ((b << 7) + myt) * 2 + sh;
    int cnt = cnts[key];
    int q = (cnt + 3) >> 2;              // per-wave chunk
    int mq = q;
#pragma unroll
    for (int m = 1; m < 16; m <<= 1) mq = max(mq, __shfl_xor(mq, m));
    const uchar_t* lst_s = sl_s + key * 64;
    const float*   lst_a = sl_av + key * 64;
    int i0 = wv * q;

    fx4 acc1[8];                 // sum_s mask*r2*h2   (per n, per col)
#pragma unroll
    for (int tile = 0; tile < 8; tile++) acc1[tile] = (fx4){0.f, 0.f, 0.f, 0.f};
    float c0 = 0.f;              // sum_s mask
    float c1 = 0.f;              // sum_s mask*r2*mean2

    for (int i = 0; i < mq; i++) {
        int idx = i0 + i;
        bool val = (i < q) && (idx < cnt);
        int ridx = (idx < cnt) ? idx : (cnt > 0 ? cnt - 1 : 0);
        int s = lst_s[ridx];
        float avv = val ? lst_a[ridx] : 0.f;
        const float* brow = base + (b * NN + s) * HH;

        // one pass: vv = relu(base + avv*w17); stats + pair-packed hi/lo
        short8 Hhi[4], Hlo[4];
        float sm = 0.f, s2 = 0.f;
#pragma unroll
        for (int st = 0; st < 4; st++) {
            const float* p = brow + quad * 8 + 32 * st;
            float4 b0 = *(const float4*)p;
            float4 b1q = *(const float4*)(p + 4);
            float h[8] = {b0.x, b0.y, b0.z, b0.w, b1q.x, b1q.y, b1q.z, b1q.w};
            uint_t hw[4], lw[4];
#pragma unroll
            for (int pr = 0; pr < 4; pr++) {
                float a = fmaxf(fmaf(avv, w17v[st][2 * pr], h[2 * pr]), 0.f);
                float c = fmaxf(fmaf(avv, w17v[st][2 * pr + 1], h[2 * pr + 1]), 0.f);
                sm += a; sm += c;
                s2 = fmaf(a, a, s2);
                s2 = fmaf(c, c, s2);
                pair_split(a, c, hw[pr], lw[pr]);
            }
            Hhi[st] = pack4(hw[0], hw[1], hw[2], hw[3]);
            Hlo[st] = pack4(lw[0], lw[1], lw[2], lw[3]);
        }
        sm += __shfl_xor(sm, 16); sm += __shfl_xor(sm, 32);
        s2 += __shfl_xor(s2, 16); s2 += __shfl_xor(s2, 32);
        float m1 = sm * (1.f / 128.f);
        float r1 = rsqrtf(s2 * (1.f / 128.f) - m1 * m1 + 1e-5f);
        float nm = -m1 * r1;

        // Graw = Wh'^T @ vv
        fx4 G[8];
#pragma unroll
        for (int tile = 0; tile < 8; tile++) G[tile] = (fx4){0.f, 0.f, 0.f, 0.f};
#pragma unroll
        for (int st = 0; st < 4; st++) {
            int koff = quad * 8 + 32 * st;
#pragma unroll
            for (int tile = 0; tile < 8; tile++) {
                int off = (tile * 16 + nl) * HH + (koff ^ (nl * 8));
                short8 ph = *(const short8*)(&Phi[off]);
                short8 pl = *(const short8*)(&Plo[off]);
                G[tile] = __builtin_amdgcn_mfma_f32_16x16x32_bf16(ph, Hhi[st], G[tile], 0, 0, 0);
                G[tile] = __builtin_amdgcn_mfma_f32_16x16x32_bf16(pl, Hhi[st], G[tile], 0, 0, 0);
                G[tile] = __builtin_amdgcn_mfma_f32_16x16x32_bf16(ph, Hlo[st], G[tile], 0, 0, 0);
            }
        }

        // LN1 correction + relu; LN2 stats (in-lane over 32 n + 2 shuffles)
        float sm2 = 0.f, ss2 = 0.f;
#pragma unroll
        for (int tile = 0; tile < 8; tile++) {
            float4 w4 = *(const float4*)(W1sg + tile * 16 + quad * 4);
            float4 c4 = *(const float4*)(cbv + tile * 16 + quad * 4);
            float wa[4] = {w4.x, w4.y, w4.z, w4.w};
            float ca[4] = {c4.x, c4.y, c4.z, c4.w};
#pragma unroll
            for (int r = 0; r < 4; r++) {
                float pre = fmaf(r1, G[tile][r], fmaf(nm, wa[r], ca[r]));
                float h2 = fmaxf(pre, 0.f);
                G[tile][r] = h2;
                sm2 += h2;
                ss2 = fmaf(h2, h2, ss2);
            }
        }
        sm2 += __shfl_xor(sm2, 16); sm2 += __shfl_xor(sm2, 32);
        ss2 += __shfl_xor(ss2, 16); ss2 += __shfl_xor(ss2, 32);
        float mean2 = sm2 * (1.f / 128.f);
        float r2 = rsqrtf(ss2 * (1.f / 128.f) - mean2 * mean2 + 1e-5f);
        float msk = val ? 1.f : 0.f;
        float mr2 = msk * r2;

#pragma unroll
        for (int tile = 0; tile < 8; tile++)
#pragma unroll
            for (int r = 0; r < 4; r++)
                acc1[tile][r] = fmaf(mr2, G[tile][r], acc1[tile][r]);
        c0 += msk;
        c1 = fmaf(mr2, mean2, c1);
    }

    // ---- epilogue: xv = gh*(acc1 - c1) + beh*c0 ;  cross-wave LDS reduce,
    //      then coalesced atomics to PERMUTED rows (row = tmap16[t]) ----
    __syncthreads();                       // Phi/Plo dead; reuse as f32 slab
    float* slab = (float*)PhiPlo;          // [4 waves][16 cols][stride 132]
#pragma unroll
    for (int tile = 0; tile < 8; tile++) {
        float4 g4 = *(const float4*)(ghp + tile * 16 + quad * 4);
        float4 be4 = *(const float4*)(behp + tile * 16 + quad * 4);
        float gv[4] = {g4.x, g4.y, g4.z, g4.w};
        float bv[4] = {be4.x, be4.y, be4.z, be4.w};
#pragma unroll
        for (int r = 0; r < 4; r++) {
            float xv = fmaf(gv[r], acc1[tile][r] - c1, bv[r] * c0);
            slab[(wv * 16 + nl) * 132 + tile * 16 + quad * 4 + r] = xv;
        }
    }
    __syncthreads();
    for (int e = tid; e < 16 * HH; e += 256) {
        int t = e >> 7, n = e & 127;
        float vsum = slab[t * 132 + n] + slab[(16 + t) * 132 + n]
                   + slab[(32 + t) * 132 + n] + slab[(48 + t) * 132 + n];
        atomicAdd(&x0[(b * NN + tmap16[t]) * HH + n], vsum);
    }
}

// ---------------- K5: qkvs via MFMA, 512 blocks, LDS-staged weights --------
// (unchanged from round 14)
template <int IN>
__global__ void __launch_bounds__(256) k_qkvs_mfma(
    const float* x, const ushort_t* Whi, const ushort_t* Wlo,
    const float* b0, const float* b1, const float* b2, const float* b3,
    float* q, float* skipo,
    ushort_t* khi, ushort_t* klo, ushort_t* vThi, ushort_t* vTlo,
    const int* agentp)
{
    const int ST = IN / 32;
    __shared__ __align__(16) ushort_t BhL[32 * IN];   // 8/16 KB
    __shared__ __align__(16) ushort_t BlL[32 * IN];

    int blk = blockIdx.x;             // 512 = 64 m-blocks * 8 col slices
    int m0 = (blk >> 3) * 64;
    int nsl = blk & 7;                // 32-col slice
    int tid = threadIdx.x;
    int wv = tid >> 6;
    int lane = tid & 63;
    int nl = lane & 15;
    int quad = lane >> 4;
    int row = m0 + wv * 16 + nl;

    short8 Ahi[ST], Alo[ST];
    const float* xrow = x + (long)row * IN;
#pragma unroll
    for (int st = 0; st < ST; st++) {
        const float* p = xrow + quad * 8 + 32 * st;
        float4 a4 = *(const float4*)p;
        float4 b4 = *(const float4*)(p + 4);
        float h[8] = {a4.x, a4.y, a4.z, a4.w, b4.x, b4.y, b4.z, b4.w};
        uint_t hw[4], lw[4];
#pragma unroll
        for (int pr = 0; pr < 4; pr++)
            pair_split(h[2 * pr], h[2 * pr + 1], hw[pr], lw[pr]);
        Ahi[st] = pack4(hw[0], hw[1], hw[2], hw[3]);
        Alo[st] = pack4(lw[0], lw[1], lw[2], lw[3]);
    }

    const float* bs_[4] = {b0, b1, b2, b3};
    int rw0 = m0 + wv * 16;                  // wave's 16-row tile start
    bool agset = (agentp != nullptr);
    int agrow = agset ? agentp[m0 >> 7] : -1;
    // wave-level: agent row in this wave's 16-row tile
    bool havea = agset && ((agrow >> 4) == ((rw0 & 127) >> 4));
    // block-level: agent row in this block's 64 rows (uniform)
    bool havea_blk = agset && ((agrow >> 6) == ((m0 & 127) >> 6));

#pragma unroll
    for (int mat = 0; mat < 4; mat++) {
        bool doMat = !((mat == 0 || mat == 3) && agset && !havea_blk);
        if (doMat) {
            const uint4* srcH = (const uint4*)(Whi + (mat * 256 + nsl * 32) * IN);
            const uint4* srcL = (const uint4*)(Wlo + (mat * 256 + nsl * 32) * IN);
            uint4* dH = (uint4*)BhL;
            uint4* dL = (uint4*)BlL;
#pragma unroll
            for (int i = tid; i < 32 * IN / 8; i += 256) {
                dH[i] = srcH[i];
                dL[i] = srcL[i];
            }
        }
        __syncthreads();

        bool doWave = doMat && !((mat == 0 || mat == 3) && agset && !havea);
        if (doWave) {
            fx4 G[2];
#pragma unroll
            for (int tile = 0; tile < 2; tile++) {
                float bc = bs_[mat][nsl * 32 + tile * 16 + nl];
                G[tile] = (fx4){bc, bc, bc, bc};
            }
#pragma unroll
            for (int st = 0; st < ST; st++) {
                int koff = quad * 8 + 32 * st;
#pragma unroll
                for (int tile = 0; tile < 2; tile++) {
                    int off = (tile * 16 + nl) * IN + (koff ^ (nl * 8));
                    short8 bh8 = *(const short8*)(&BhL[off]);
                    short8 bl8 = *(const short8*)(&BlL[off]);
                    G[tile] = __builtin_amdgcn_mfma_f32_16x16x32_bf16(Ahi[st], bh8, G[tile], 0, 0, 0);
                    G[tile] = __builtin_amdgcn_mfma_f32_16x16x32_bf16(Alo[st], bh8, G[tile], 0, 0, 0);
                    G[tile] = __builtin_amdgcn_mfma_f32_16x16x32_bf16(Ahi[st], bl8, G[tile], 0, 0, 0);
                }
            }
            int row0 = m0 + wv * 16 + quad * 4;          // rows r=0..3
            if (mat == 0 || mat == 3) {
                float* om = (mat == 0) ? q : skipo;
#pragma unroll
                for (int tile = 0; tile < 2; tile++)
#pragma unroll
                    for (int r = 0; r < 4; r++)
                        om[(row0 + r) * HD + nsl * 32 + tile * 16 + nl] = G[tile][r];
            } else if (mat == 1) {
                // K planes, layout [row=b*128+s][256]
#pragma unroll
                for (int tile = 0; tile < 2; tile++) {
                    int col = nsl * 32 + tile * 16 + nl;
#pragma unroll
                    for (int r = 0; r < 4; r++) {
                        float gv = G[tile][r];
                        ushort_t hb = f2us_tr(gv);
                        khi[(row0 + r) * HD + col] = hb;
                        klo[(row0 + r) * HD + col] = f2us_tr(gv - us2f(hb));
                    }
                }
            } else {
                // vT planes: vT[dg = b*256 + col][128 s], 4 consecutive s
                int bb = row0 >> 7;
                int s0 = row0 & 127;
#pragma unroll
                for (int tile = 0; tile < 2; tile++) {
                    int col = nsl * 32 + tile * 16 + nl;
                    int dg = bb * 256 + col;
                    ushort4 h4, l4;
                    float g0 = G[tile][0], g1 = G[tile][1], g2 = G[tile][2], g3 = G[tile][3];
                    ushort_t h0 = f2us_tr(g0), h1 = f2us_tr(g1), h2 = f2us_tr(g2), h3 = f2us_tr(g3);
                    h4.x = h0; h4.y = h1; h4.z = h2; h4.w = h3;
                    l4.x = f2us_tr(g0 - us2f(h0));
                    l4.y = f2us_tr(g1 - us2f(h1));
                    l4.z = f2us_tr(g2 - us2f(h2));
                    l4.w = f2us_tr(g3 - us2f(h3));
                    *(ushort4*)&vThi[dg * NN + s0] = h4;
                    *(ushort4*)&vTlo[dg * NN + s0] = l4;
                }
            }
        }
        __syncthreads();
    }
}

// ---------------- K6: attention via MFMA, 4 waves per (b,h,16-t tile) ------
// (unchanged from round 13)
__global__ void __launch_bounds__(256) k_attn_mfma(
    const float* qb, const ushort_t* khi, const ushort_t* klo,
    const ushort_t* vThi, const ushort_t* vTlo,
    const float* adjvT, const float* We, const float* skip, float* xout,
    const int* agentp, float* outp)
{
    __shared__ float aL[16][132];     // alpha C->A round-trip (8.4 KB)
    __shared__ float qeL[16];
    __shared__ float mxL[4][16];
    __shared__ float dnL[4][16];
    __shared__ float ebL[4][16];

    int blk = blockIdx.x;
    int b, h, tt;
    if (agentp == nullptr) {          // 1024 = 32b*4h*8tt
        b = blk >> 5; h = (blk >> 3) & 3; tt = blk & 7;
    } else {                          // 128 = 32b*4h
        b = blk >> 2; h = blk & 3; tt = agentp[b] >> 4;
    }
    int t0 = tt * 16;
    int tid = threadIdx.x;
    int w   = tid >> 6;               // wave 0..3
    int lane = tid & 63;
    int nl = lane & 15;
    int quad = lane >> 4;

    // ---- Q A-frags (split hi/lo) + qe partial (q . we) ----
    short8 Qhi[2], Qlo[2];
    float qe = 0.f;
#pragma unroll
    for (int ks = 0; ks < 2; ks++) {
        const float* p = qb + (b * NN + t0 + nl) * HD + h * DHEAD + quad * 8 + 32 * ks;
        const float* wp = We + h * DHEAD + quad * 8 + 32 * ks;
        float4 a0 = *(const float4*)p;
        float4 a1 = *(const float4*)(p + 4);
        float4 w0 = *(const float4*)wp;
        float4 w1 = *(const float4*)(wp + 4);
        float hv[8] = {a0.x, a0.y, a0.z, a0.w, a1.x, a1.y, a1.z, a1.w};
        float wv8[8] = {w0.x, w0.y, w0.z, w0.w, w1.x, w1.y, w1.z, w1.w};
        uint_t hw[4], lw[4];
#pragma unroll
        for (int pr = 0; pr < 4; pr++) {
            float a = hv[2 * pr], c = hv[2 * pr + 1];
            qe = fmaf(a, wv8[2 * pr], qe);
            qe = fmaf(c, wv8[2 * pr + 1], qe);
            pair_split(a, c, hw[pr], lw[pr]);
        }
        Qhi[ks] = pack4(hw[0], hw[1], hw[2], hw[3]);
        Qlo[ks] = pack4(lw[0], lw[1], lw[2], lw[3]);
    }
    qe += __shfl_xor(qe, 16);
    qe += __shfl_xor(qe, 32);
    if (w == 0 && lane < 16) qeL[lane] = qe;   // qe for t = lane
    __syncthreads();
    float qe_r[4];
#pragma unroll
    for (int r = 0; r < 4; r++) qe_r[r] = qeL[quad * 4 + r];
    float we_dv = We[h * DHEAD + w * 16 + nl];

    // ---- QK^T: wave's 2 s-tiles (global st = w*2 + st') ----
    fx4 S[2];
#pragma unroll
    for (int st = 0; st < 2; st++) S[st] = (fx4){0.f, 0.f, 0.f, 0.f};
#pragma unroll
    for (int ks = 0; ks < 2; ks++) {
#pragma unroll
        for (int st = 0; st < 2; st++) {
            long off = (long)(b * NN + (w * 2 + st) * 16 + nl) * HD + h * DHEAD + quad * 8 + 32 * ks;
            short8 bh8 = *(const short8*)(khi + off);
            short8 bl8 = *(const short8*)(klo + off);
            S[st] = __builtin_amdgcn_mfma_f32_16x16x32_bf16(Qhi[ks], bh8, S[st], 0, 0, 0);
            S[st] = __builtin_amdgcn_mfma_f32_16x16x32_bf16(Qlo[ks], bh8, S[st], 0, 0, 0);
            S[st] = __builtin_amdgcn_mfma_f32_16x16x32_bf16(Qhi[ks], bl8, S[st], 0, 0, 0);
        }
    }

    // ---- masked logits (D-layout: row t = quad*4+r, col s = (w*2+st)*16+nl)
    float av[2][4];
#pragma unroll
    for (int st = 0; st < 2; st++)
#pragma unroll
        for (int r = 0; r < 4; r++)
            av[st][r] = adjvT[(b * NN + t0 + quad * 4 + r) * NN + (w * 2 + st) * 16 + nl];
#pragma unroll
    for (int st = 0; st < 2; st++)
#pragma unroll
        for (int r = 0; r < 4; r++) {
            float a = av[st][r];
            S[st][r] = (a != 0.f) ? (S[st][r] + a * qe_r[r]) * 0.125f : -1e30f;
        }

    // ---- partial row max, combine across 4 waves ----
    float mxp[4];
#pragma unroll
    for (int r = 0; r < 4; r++) {
        float m = fmaxf(S[0][r], S[1][r]);
#pragma unroll
        for (int mm = 1; mm < 16; mm <<= 1) m = fmaxf(m, __shfl_xor(m, mm));
        mxp[r] = m;
    }
    if (nl == 0) {
#pragma unroll
        for (int r = 0; r < 4; r++) mxL[w][quad * 4 + r] = mxp[r];
    }
    __syncthreads();
    float mx[4];
#pragma unroll
    for (int r = 0; r < 4; r++) {
        int row = quad * 4 + r;
        mx[r] = fmaxf(fmaxf(mxL[0][row], mxL[1][row]),
                      fmaxf(mxL[2][row], mxL[3][row]));
    }

    // ---- e = exp(S - mx); partial den & e.av, combine ----
    float dnp[4] = {0.f, 0.f, 0.f, 0.f}, ebp[4] = {0.f, 0.f, 0.f, 0.f};
#pragma unroll
    for (int st = 0; st < 2; st++)
#pragma unroll
        for (int r = 0; r < 4; r++) {
            float e = (av[st][r] != 0.f) ? __expf(S[st][r] - mx[r]) : 0.f;
            S[st][r] = e;
            dnp[r] += e;
            ebp[r] = fmaf(e, av[st][r], ebp[r]);
        }
#pragma unroll
    for (int r = 0; r < 4; r++) {
#pragma unroll
        for (int mm = 1; mm < 16; mm <<= 1) {
            dnp[r] += __shfl_xor(dnp[r], mm);
            ebp[r] += __shfl_xor(ebp[r], mm);
        }
    }
    if (nl == 0) {
#pragma unroll
        for (int r = 0; r < 4; r++) {
            dnL[w][quad * 4 + r] = dnp[r];
            ebL[w][quad * 4 + r] = ebp[r];
        }
    }
    __syncthreads();
    float rden[4], beta[4];
#pragma unroll
    for (int r = 0; r < 4; r++) {
        int row = quad * 4 + r;
        float d = ((dnL[0][row] + dnL[1][row]) + dnL[2][row]) + dnL[3][row];
        rden[r] = 1.f / fmaxf(d, 1e-16f);
        beta[r] = (((ebL[0][row] + ebL[1][row]) + ebL[2][row]) + ebL[3][row]) * rden[r];
    }

    // ---- alpha -> aL (wave writes its 32-column slice) ----
#pragma unroll
    for (int st = 0; st < 2; st++)
#pragma unroll
        for (int r = 0; r < 4; r++)
            aL[quad * 4 + r][(w * 2 + st) * 16 + nl] = S[st][r] * rden[r];
    __syncthreads();

    // ---- A-frags over full s range ----
    short8 Ah[4];
#pragma unroll
    for (int ks = 0; ks < 4; ks++) {
        const float* p = &aL[nl][quad * 8 + 32 * ks];
        float4 a0 = *(const float4*)p;
        float4 a1 = *(const float4*)(p + 4);
        float hv[8] = {a0.x, a0.y, a0.z, a0.w, a1.x, a1.y, a1.z, a1.w};
        uint_t ww[4];
#pragma unroll
        for (int pr = 0; pr < 4; pr++) ww[pr] = pair_hi(hv[2 * pr], hv[2 * pr + 1]);
        Ah[ks] = pack4(ww[0], ww[1], ww[2], ww[3]);
    }

    // ---- PV: wave's output-d quarter (nt = w) ----
    fx4 G;
#pragma unroll
    for (int r = 0; r < 4; r++) G[r] = beta[r] * we_dv;
    {
        long dg = (long)(b * 256 + h * DHEAD + w * 16 + nl);
        const ushort_t* vhB = vThi + dg * NN;
        const ushort_t* vlB = vTlo + dg * NN;
#pragma unroll
        for (int ks = 0; ks < 4; ks++) {
            const short8 vh = *(const short8*)(vhB + quad * 8 + 32 * ks);
            const short8 vl = *(const short8*)(vlB + quad * 8 + 32 * ks);
            G = __builtin_amdgcn_mfma_f32_16x16x32_bf16(Ah[ks], vh, G, 0, 0, 0);
            G = __builtin_amdgcn_mfma_f32_16x16x32_bf16(Ah[ks], vl, G, 0, 0, 0);
        }
    }

    // ---- epilogue ----
    if (agentp == nullptr) {
        // layer 1: full relu(out + skip) -> xout
#pragma unroll
        for (int r = 0; r < 4; r++) {
            int gi = (b * NN + t0 + quad * 4 + r) * HD + h * DHEAD + w * 16 + nl;
            xout[gi] = fmaxf(G[r] + skip[gi], 0.f);
        }
    } else {
        // layer 2 + fused gather: only the agent row reaches the output
        int ag = agentp[b];
#pragma unroll
        for (int r = 0; r < 4; r++) {
            int t = t0 + quad * 4 + r;
            if (t == ag) {
                int d = h * DHEAD + w * 16 + nl;
                int gi = (b * NN + t) * HD + d;
                outp[b * HD + d] = fmaxf(G[r] + skip[gi], 0.f);
            }
        }
    }
}

// ---------------- launch ----------------
extern "C" void kernel_launch(void* const* d_in, const int* in_sizes, int n_in,
                              void* d_out, int out_size, void* d_ws, size_t ws_size,
                              hipStream_t stream) {
    float* out = (float*)d_out;
    (void)hipGetLastError();

    bool ok = (n_in == 31) && in_sizes[0] == BB * NN * FF && in_sizes[2] == BB * NN * NN
              && in_sizes[5] == (FF + EE + 1) * HH && in_sizes[13] == HH * HD
              && in_sizes[22] == HD * HD && out_size == BB * HD;
    if (!ok) { k_sent<<<32, 256, 0, stream>>>(out, -30000.f); return; }

    const size_t WS_NEED = (size_t)8912896 * 4;
    if (ws_size < WS_NEED) { k_sent<<<32, 256, 0, stream>>>(out, -20000.f); return; }

    const float* nf    = (const float*)d_in[0];
    const int*   et    = (const int*)d_in[1];
    const float* adj   = (const float*)d_in[2];
    const int*   agent = (const int*)d_in[3];
    const float* emb   = (const float*)d_in[4];
    const float* W1    = (const float*)d_in[5];
    const float* b1    = (const float*)d_in[6];
    const float* g1    = (const float*)d_in[7];
    const float* be1   = (const float*)d_in[8];
    const float* Wh    = (const float*)d_in[9];
    const float* bh    = (const float*)d_in[10];
    const float* gh    = (const float*)d_in[11];
    const float* beh   = (const float*)d_in[12];
    const float* Wq1   = (const float*)d_in[13];
    const float* bq1   = (const float*)d_in[14];
    const float* Wk1   = (const float*)d_in[15];
    const float* bk1   = (const float*)d_in[16];
    const float* Wv1   = (const float*)d_in[17];
    const float* bv1   = (const float*)d_in[18];
    const float* We1   = (const float*)d_in[19];
    const float* Ws1   = (const float*)d_in[20];
    const float* bs1   = (const float*)d_in[21];
    const float* Wq2   = (const float*)d_in[22];
    const float* bq2   = (const float*)d_in[23];
    const float* Wk2   = (const float*)d_in[24];
    const float* bk2   = (const float*)d_in[25];
    const float* Wv2   = (const float*)d_in[26];
    const float* bv2   = (const float*)d_in[27];
    const float* We2   = (const float*)d_in[28];
    const float* Ws2   = (const float*)d_in[29];
    const float* bs2   = (const float*)d_in[30];

    float* ws   = (float*)d_ws;
    float* slav = ws;                              // 524288 f region (sl_av)
    float* base = ws + 524288;                     // 524288 f
    float* x0   = base + BB * NN * HH;             // 524288 f
    float* q    = x0 + BB * NN * HH;               // 1048576 f
    float* kreg = q + BB * NN * HD;                // 1048576 f -> khi/klo
    float* vreg = kreg + BB * NN * HD;             // 1048576 f -> vThi/vTlo
    float* skip = vreg + BB * NN * HD;             // 1048576 f
    float* areg = skip + BB * NN * HD;             // 1048576 f -> planes + adjvT + sl_s
    float* x1   = areg + BB * NN * HD;
    float* x2   = x1 + BB * NN * HD;

    // econv prep planes in q region (q first written AFTER econv)
    ushort_t* BhiG = (ushort_t*)q;
    ushort_t* BloG = BhiG + HH * HH;
    float*    W1sW = q + 16384;
    float*    cbW  = q + 16512;
    int*      cnts = (int*)(q + 17024);            // 8192 ints
    int*      tmapG = (int*)(q + 25216);           // 8192 ints (rank -> t)

    // K / vT planes
    ushort_t* khi  = (ushort_t*)kreg;              // 1048576 ush
    ushort_t* klo  = khi + BB * NN * HD;           // 1048576 ush
    ushort_t* vThi = (ushort_t*)vreg;
    ushort_t* vTlo = vThi + BB * NN * HD;

    // qkvs weight planes + adjvT + sl_s in areg (4 MB):
    // planes 1.5 MB + adjvT 2 MB + sl_s 0.5 MB = 4 MB exactly
    ushort_t* WhA = (ushort_t*)areg;               // 4*256*128 ush
    ushort_t* WlA = WhA + 4 * 256 * HH;
    ushort_t* WhB = WlA + 4 * 256 * HH;            // 4*256*256 ush
    ushort_t* WlB = WhB + 4 * 256 * HD;
    float* adjvT  = areg + 393216;                 // 524288 f, past planes
    uchar_t* sl_s = (uchar_t*)(areg + 917504);     // 524288 uchars, tail

    int fail = 0;
    hipError_t e;
#define CHK(stage) do { e = hipGetLastError(); if (e != hipSuccess && fail == 0) fail = (stage); } while (0)

    k_prep_all<<<1472, 256, 0, stream>>>(
        adj, adjvT, sl_s, slav, cnts, tmapG,
        nf, et, emb, W1, b1, base, x0,
        Wh, g1, be1, bh, BhiG, BloG, W1sW, cbW);                                     CHK(1);

    k_econv_mfma<<<1024, 256, 0, stream>>>(sl_s, slav, cnts, tmapG, base, W1,
                                           BhiG, BloG, W1sW, cbW, gh, beh, x0,
                                           Wq1, Wk1, Wv1, Ws1, WhA, WlA,
                                           Wq2, Wk2, Wv2, Ws2, WhB, WlB);            CHK(2);

    k_qkvs_mfma<HH><<<512, 256, 0, stream>>>(x0, WhA, WlA, bq1, bk1, bv1, bs1,
                                             q, skip, khi, klo, vThi, vTlo,
                                             nullptr);                               CHK(3);
    k_attn_mfma<<<1024, 256, 0, stream>>>(q, khi, klo, vThi, vTlo, adjvT, We1,
                                          skip, x1, nullptr, nullptr);               CHK(4);

    k_qkvs_mfma<HD><<<512, 256, 0, stream>>>(x1, WhB, WlB, bq2, bk2, bv2, bs2,
                                             q, skip, khi, klo, vThi, vTlo,
                                             agent);                                 CHK(5);
    k_attn_mfma<<<128, 256, 0, stream>>>(q, khi, klo, vThi, vTlo, adjvT, We2,
                                         skip, x2, agent, out);                      CHK(6);
#undef CHK

    if (fail != 0)
        k_sent<<<32, 256, 0, stream>>>(out, -(1000.f + 500.f * (float)fail));
}